// Round 1
// baseline (1599.360 us; speedup 1.0000x reference)
//
#include <hip/hip_runtime.h>

// Problem constants (fixed by reference)
#define NN 50000      // nodes
#define NE 800000     // edges
#define DD 256        // node feat dim
#define GFEAT 200     // graph feat dim
#define NG 512        // graphs

// ---------------------------------------------------------------------------
// small utility kernels
// ---------------------------------------------------------------------------
__global__ __launch_bounds__(256) void zero_ints_kernel(int* __restrict__ p, int n) {
    int i = blockIdx.x * 256 + threadIdx.x;
    if (i < n) p[i] = 0;
}

__global__ __launch_bounds__(256) void hist_kernel(const int* __restrict__ dst,
                                                   int* __restrict__ counts, int n) {
    int e = blockIdx.x * 256 + threadIdx.x;
    if (e < n) atomicAdd(&counts[dst[e]], 1);
}

// single-block exclusive scan over n counts (in place), also copies to cursor.
// io has n+1 entries; io[n] = total on exit.
__global__ __launch_bounds__(1024) void scan_kernel(int* __restrict__ io,
                                                    int* __restrict__ cursor, int n) {
    __shared__ int sdata[1024];
    __shared__ int carry_s;
    int t = threadIdx.x;
    if (t == 0) carry_s = 0;
    __syncthreads();
    for (int base = 0; base < n; base += 1024) {
        int x = (base + t < n) ? io[base + t] : 0;
        sdata[t] = x;
        __syncthreads();
        for (int off = 1; off < 1024; off <<= 1) {
            int v = (t >= off) ? sdata[t - off] : 0;
            __syncthreads();
            sdata[t] += v;
            __syncthreads();
        }
        int incl  = sdata[t];
        int excl  = incl - x;
        int carry = carry_s;
        if (base + t < n) {
            io[base + t]     = carry + excl;
            cursor[base + t] = carry + excl;
        }
        __syncthreads();
        if (t == 1023) carry_s = carry + incl;
        __syncthreads();
    }
    if (t == 0) io[n] = carry_s;
}

__global__ __launch_bounds__(256) void scatter_kernel(const int* __restrict__ src,
                                                      const int* __restrict__ dst,
                                                      int* __restrict__ cursor,
                                                      int* __restrict__ csr, int n) {
    int e = blockIdx.x * 256 + threadIdx.x;
    if (e < n) {
        int pos = atomicAdd(&cursor[dst[e]], 1);
        csr[pos] = src[e];
    }
}

// ---------------------------------------------------------------------------
// fp32 tiled GEMM: C[M,N] = A[M,K] @ B[K,N] (+bias) (+relu)
// 64x64 tile, BK=16, 256 threads, 4x4 outputs/thread.
// ---------------------------------------------------------------------------
__global__ __launch_bounds__(256) void gemm_kernel(const float* __restrict__ A,
                                                   const float* __restrict__ B,
                                                   const float* __restrict__ bias,
                                                   float* __restrict__ C,
                                                   int M, int N, int K, int do_relu) {
    __shared__ float As[16][68];   // [k][m], padded to 68 (272B rows keep 16B align)
    __shared__ float Bs[16][68];   // [k][n]

    const int t    = threadIdx.x;
    const int row0 = blockIdx.y * 64;
    const int col0 = blockIdx.x * 64;

    const int aRow = t >> 2;         // 0..63
    const int aCol = (t & 3) * 4;    // 0,4,8,12
    const int bRow = t >> 4;         // 0..15
    const int bCol = (t & 15) * 4;   // 0..60

    const int tr = (t >> 4) * 4;     // thread's row offset in tile
    const int tc = (t & 15) * 4;     // thread's col offset in tile

    float acc[4][4];
#pragma unroll
    for (int i = 0; i < 4; i++)
#pragma unroll
        for (int j = 0; j < 4; j++) acc[i][j] = 0.f;

    for (int k0 = 0; k0 < K; k0 += 16) {
        // stage A tile (transposed into As[k][m])
        float4 av = make_float4(0.f, 0.f, 0.f, 0.f);
        int ar = row0 + aRow;
        if (ar < M) av = *(const float4*)&A[(size_t)ar * K + k0 + aCol];
        As[aCol + 0][aRow] = av.x;
        As[aCol + 1][aRow] = av.y;
        As[aCol + 2][aRow] = av.z;
        As[aCol + 3][aRow] = av.w;
        // stage B tile
        float4 bv = make_float4(0.f, 0.f, 0.f, 0.f);
        int bc = col0 + bCol;
        if (bc < N) bv = *(const float4*)&B[(size_t)(k0 + bRow) * N + bc];
        *(float4*)&Bs[bRow][bCol] = bv;
        __syncthreads();

#pragma unroll
        for (int kk = 0; kk < 16; kk++) {
            float4 a = *(const float4*)&As[kk][tr];
            float4 b = *(const float4*)&Bs[kk][tc];
            acc[0][0] += a.x * b.x; acc[0][1] += a.x * b.y; acc[0][2] += a.x * b.z; acc[0][3] += a.x * b.w;
            acc[1][0] += a.y * b.x; acc[1][1] += a.y * b.y; acc[1][2] += a.y * b.z; acc[1][3] += a.y * b.w;
            acc[2][0] += a.z * b.x; acc[2][1] += a.z * b.y; acc[2][2] += a.z * b.z; acc[2][3] += a.z * b.w;
            acc[3][0] += a.w * b.x; acc[3][1] += a.w * b.y; acc[3][2] += a.w * b.z; acc[3][3] += a.w * b.w;
        }
        __syncthreads();
    }

    const int c = col0 + tc;
    if (c < N) {
        float4 bv = make_float4(0.f, 0.f, 0.f, 0.f);
        if (bias) bv = *(const float4*)&bias[c];
#pragma unroll
        for (int i = 0; i < 4; i++) {
            int r = row0 + tr + i;
            if (r < M) {
                float4 o;
                o.x = acc[i][0] + bv.x;
                o.y = acc[i][1] + bv.y;
                o.z = acc[i][2] + bv.z;
                o.w = acc[i][3] + bv.w;
                if (do_relu) {
                    o.x = fmaxf(o.x, 0.f); o.y = fmaxf(o.y, 0.f);
                    o.z = fmaxf(o.z, 0.f); o.w = fmaxf(o.w, 0.f);
                }
                *(float4*)&C[(size_t)r * N + c] = o;
            }
        }
    }
}

// ---------------------------------------------------------------------------
// edge aggregation + combine: H[v] = relu(sum_{e: dst=v} hW[src[e]] + b) + res[v]
// one wave per dst node; lane holds 4 feats (float4).
// ---------------------------------------------------------------------------
__global__ __launch_bounds__(256) void agg_combine_kernel(const float* __restrict__ hW,
                                                          const int* __restrict__ csr_src,
                                                          const int* __restrict__ offsets,
                                                          const float* __restrict__ bias,
                                                          const float* __restrict__ res,
                                                          float* __restrict__ H, int n_nodes) {
    int wave = threadIdx.x >> 6;
    int lane = threadIdx.x & 63;
    int node = blockIdx.x * 4 + wave;
    if (node >= n_nodes) return;
    int beg = offsets[node], end = offsets[node + 1];
    float4 acc = make_float4(0.f, 0.f, 0.f, 0.f);
    for (int j = beg; j < end; j++) {
        int s = csr_src[j];  // wave-uniform
        float4 v = *(const float4*)&hW[(size_t)s * DD + lane * 4];
        acc.x += v.x; acc.y += v.y; acc.z += v.z; acc.w += v.w;
    }
    float4 b = *(const float4*)&bias[lane * 4];
    float4 r = *(const float4*)&res[(size_t)node * DD + lane * 4];
    float4 o;
    o.x = fmaxf(acc.x + b.x, 0.f) + r.x;
    o.y = fmaxf(acc.y + b.y, 0.f) + r.y;
    o.z = fmaxf(acc.z + b.z, 0.f) + r.z;
    o.w = fmaxf(acc.w + b.w, 0.f) + r.w;
    *(float4*)&H[(size_t)node * DD + lane * 4] = o;
}

// ---------------------------------------------------------------------------
// per-graph segment sum of P[N, GFEAT] using sorted graph_ids; block per graph
// ---------------------------------------------------------------------------
__global__ __launch_bounds__(256) void graph_reduce_kernel(const float* __restrict__ P,
                                                           const int* __restrict__ gids,
                                                           float* __restrict__ G, int n_nodes) {
    int g = blockIdx.x;
    // lower_bound(g) and lower_bound(g+1)
    int lo = 0, hi = n_nodes;
    while (lo < hi) { int mid = (lo + hi) >> 1; if (gids[mid] < g) lo = mid + 1; else hi = mid; }
    int beg = lo;
    hi = n_nodes;
    while (lo < hi) { int mid = (lo + hi) >> 1; if (gids[mid] < g + 1) lo = mid + 1; else hi = mid; }
    int end = lo;

    int c = threadIdx.x;
    if (c < GFEAT) {
        float acc = 0.f;
        for (int r = beg; r < end; r++) acc += P[(size_t)r * GFEAT + c];
        G[(size_t)g * GFEAT + c] = acc;
    }
}

__global__ __launch_bounds__(256) void predictor_kernel(const float* __restrict__ G1,
                                                        const float* __restrict__ G2,
                                                        const float* __restrict__ Wp,
                                                        const float* __restrict__ bp,
                                                        float* __restrict__ out) {
    int i = blockIdx.x * 256 + threadIdx.x;
    if (i >= NG) return;
    float acc = bp[0];
    for (int f = 0; f < GFEAT; f++)
        acc += (G1[i * GFEAT + f] + G2[i * GFEAT + f]) * Wp[f];
    out[i] = acc;
}

// ---------------------------------------------------------------------------
// host-side branch driver
// ---------------------------------------------------------------------------
static void run_branch(const float* X, const int* src, const int* dst, const int* gids,
                       const float* W, const float* b, const float* Wr, const float* br,
                       const float* Ri, const float* rbi, const float* Ro, const float* rbo,
                       float* Gout, float* bufA, float* bufB, float* bufC,
                       int* offs, int* cursor, int* csr, hipStream_t stream) {
    // CSR by dst
    zero_ints_kernel<<<(NN + 1 + 255) / 256, 256, 0, stream>>>(offs, NN + 1);
    hist_kernel<<<(NE + 255) / 256, 256, 0, stream>>>(dst, offs, NE);
    scan_kernel<<<1, 1024, 0, stream>>>(offs, cursor, NN);
    scatter_kernel<<<(NE + 255) / 256, 256, 0, stream>>>(src, dst, cursor, csr, NE);

    dim3 g256((DD + 63) / 64, (NN + 63) / 64);
    dim3 g200((GFEAT + 63) / 64, (NN + 63) / 64);
    // hW = X @ W             -> bufA
    gemm_kernel<<<g256, 256, 0, stream>>>(X, W, nullptr, bufA, NN, DD, DD, 0);
    // res = relu(X @ Wr+br)  -> bufB
    gemm_kernel<<<g256, 256, 0, stream>>>(X, Wr, br, bufB, NN, DD, DD, 1);
    // H = relu(agg + b) + res -> bufC
    agg_combine_kernel<<<(NN + 3) / 4, 256, 0, stream>>>(bufA, csr, offs, b, bufB, bufC, NN);
    // R = relu(H @ Ri + rbi) -> bufA
    gemm_kernel<<<g256, 256, 0, stream>>>(bufC, Ri, rbi, bufA, NN, DD, DD, 1);
    // P = R @ Ro + rbo       -> bufB
    gemm_kernel<<<g200, 256, 0, stream>>>(bufA, Ro, rbo, bufB, NN, GFEAT, DD, 0);
    // G = segment_sum(P, gids)
    graph_reduce_kernel<<<NG, 256, 0, stream>>>(bufB, gids, Gout, NN);
}

extern "C" void kernel_launch(void* const* d_in, const int* in_sizes, int n_in,
                              void* d_out, int out_size, void* d_ws, size_t ws_size,
                              hipStream_t stream) {
    const float* X1   = (const float*)d_in[0];
    const float* X2   = (const float*)d_in[2];
    const int*   src1 = (const int*)d_in[4];
    const int*   dst1 = (const int*)d_in[5];
    const int*   gid1 = (const int*)d_in[6];
    const int*   src2 = (const int*)d_in[7];
    const int*   dst2 = (const int*)d_in[8];
    const int*   gid2 = (const int*)d_in[9];
    const float* W1  = (const float*)d_in[10]; const float* b1  = (const float*)d_in[11];
    const float* Wr1 = (const float*)d_in[12]; const float* br1 = (const float*)d_in[13];
    const float* W2  = (const float*)d_in[14]; const float* b2  = (const float*)d_in[15];
    const float* Wr2 = (const float*)d_in[16]; const float* br2 = (const float*)d_in[17];
    const float* Ri1 = (const float*)d_in[18]; const float* rbi1 = (const float*)d_in[19];
    const float* Ro1 = (const float*)d_in[20]; const float* rbo1 = (const float*)d_in[21];
    const float* Ri2 = (const float*)d_in[22]; const float* rbi2 = (const float*)d_in[23];
    const float* Ro2 = (const float*)d_in[24]; const float* rbo2 = (const float*)d_in[25];
    const float* Wp  = (const float*)d_in[26]; const float* bp  = (const float*)d_in[27];

    // workspace layout
    float* bufA = (float*)d_ws;                       // 50000*256
    float* bufB = bufA + (size_t)NN * DD;             // 50000*256
    float* bufC = bufB + (size_t)NN * DD;             // 50000*256
    float* G1   = bufC + (size_t)NN * DD;             // 512*200
    float* G2   = G1 + (size_t)NG * GFEAT;            // 512*200
    int*   offs   = (int*)(G2 + (size_t)NG * GFEAT);  // 50001
    int*   cursor = offs + (NN + 1);                  // 50000
    int*   csr    = cursor + NN;                      // 800000

    run_branch(X1, src1, dst1, gid1, W1, b1, Wr1, br1, Ri1, rbi1, Ro1, rbo1,
               G1, bufA, bufB, bufC, offs, cursor, csr, stream);
    run_branch(X2, src2, dst2, gid2, W2, b2, Wr2, br2, Ri2, rbi2, Ro2, rbo2,
               G2, bufA, bufB, bufC, offs, cursor, csr, stream);

    predictor_kernel<<<(NG + 255) / 256, 256, 0, stream>>>(G1, G2, Wp, bp, (float*)d_out);
}

// Round 2
// 1196.651 us; speedup vs baseline: 1.3365x; 1.3365x over previous
//
#include <hip/hip_runtime.h>

// Problem constants (fixed by reference)
#define NN 50000      // nodes
#define NE 800000     // edges
#define DD 256        // node feat dim
#define GFEAT 200     // graph feat dim
#define NG 512        // graphs

typedef __bf16 bf16;
typedef bf16 bf16x4 __attribute__((ext_vector_type(4)));
typedef bf16 bf16x8 __attribute__((ext_vector_type(8)));
typedef float f32x4 __attribute__((ext_vector_type(4)));

// async global->LDS, 16B per lane. HW dest = wave-uniform base + lane*16.
__device__ __forceinline__ void gl_lds16(const bf16* g, bf16* l) {
    __builtin_amdgcn_global_load_lds(
        (const __attribute__((address_space(1))) uint32_t*)(g),
        (__attribute__((address_space(3))) uint32_t*)(l), 16, 0, 0);
}

// ---------------------------------------------------------------------------
// conversions
// ---------------------------------------------------------------------------
__global__ __launch_bounds__(256) void conv_x_kernel(const float* __restrict__ in,
                                                     bf16* __restrict__ out, int n4) {
    int i = blockIdx.x * 256 + threadIdx.x;
    if (i < n4) {
        float4 v = ((const float4*)in)[i];
        bf16x4 o;
        o[0] = (bf16)v.x; o[1] = (bf16)v.y; o[2] = (bf16)v.z; o[3] = (bf16)v.w;
        ((bf16x4*)out)[i] = o;
    }
}

// in: fp32 [256][N] row-major; out: bf16 [256][256] = [n][k] (transposed, zero-padded)
__global__ __launch_bounds__(256) void conv_w_kernel(const float* __restrict__ in,
                                                     bf16* __restrict__ out, int N) {
    int idx = blockIdx.x * 256 + threadIdx.x;   // 0..65535 over [n][k]
    int n = idx >> 8, k = idx & 255;
    float v = (n < N) ? in[k * N + n] : 0.f;
    out[idx] = (bf16)v;
}

// ---------------------------------------------------------------------------
// CSR build
// ---------------------------------------------------------------------------
__global__ __launch_bounds__(256) void zero_ints_kernel(int* __restrict__ p, int n) {
    int i = blockIdx.x * 256 + threadIdx.x;
    if (i < n) p[i] = 0;
}

__global__ __launch_bounds__(256) void hist_kernel(const int* __restrict__ dst,
                                                   int* __restrict__ counts, int n) {
    int e = blockIdx.x * 256 + threadIdx.x;
    if (e < n) atomicAdd(&counts[dst[e]], 1);
}

// single-block chunked scan: each thread owns ceil(n/1024) elements.
__global__ __launch_bounds__(1024) void scan_kernel(int* __restrict__ io,
                                                    int* __restrict__ cursor, int n) {
    __shared__ int partial[1024];
    int t = threadIdx.x;
    const int chunk = (n + 1023) / 1024;
    int beg = t * chunk;
    int end = beg + chunk; if (end > n) end = n;
    int s = 0;
    for (int i = beg; i < end; i++) s += io[i];
    partial[t] = s;
    __syncthreads();
    for (int off = 1; off < 1024; off <<= 1) {
        int v = (t >= off) ? partial[t - off] : 0;
        __syncthreads();
        partial[t] += v;
        __syncthreads();
    }
    int run = partial[t] - s;   // exclusive prefix at chunk start
    for (int i = beg; i < end; i++) {
        int c = io[i];
        io[i] = run; cursor[i] = run;
        run += c;
    }
    __syncthreads();
    if (t == 0) io[n] = partial[1023];
}

__global__ __launch_bounds__(256) void scatter_kernel(const int* __restrict__ src,
                                                      const int* __restrict__ dst,
                                                      int* __restrict__ cursor,
                                                      int* __restrict__ csr, int n) {
    int e = blockIdx.x * 256 + threadIdx.x;
    if (e < n) {
        int pos = atomicAdd(&cursor[dst[e]], 1);
        csr[pos] = src[e];
    }
}

// ---------------------------------------------------------------------------
// bf16 MFMA GEMM: C[M,N] = A[M,K] @ Bt[N,K]^T (+bias) (+relu)
// 128x128 tile, BK=32, 256 threads (4 waves, 2x2), 4x4 16x16x32 MFMAs per wave.
// Bt must be padded to gridDim.x*128 rows. flags: bit0 = relu, bit1 = bf16 out.
// ---------------------------------------------------------------------------
__global__ __launch_bounds__(256) void mfma_gemm_kernel(
    const bf16* __restrict__ A, const bf16* __restrict__ Bt,
    const float* __restrict__ bias, void* __restrict__ Cout,
    int M, int N, int K, int flags) {
    __shared__ bf16 As[128 * 32];   // [m][k]
    __shared__ bf16 Bs[128 * 32];   // [n][k]

    const int t    = threadIdx.x;
    const int lane = t & 63;
    const int w    = t >> 6;
    const int row0 = blockIdx.y * 128;
    const int col0 = blockIdx.x * 128;

    f32x4 acc[4][4] = {};

    const int wm = (w >> 1) * 64, wn = (w & 1) * 64;
    const int fm = lane & 15, fk = (lane >> 4) * 8;

    for (int k0 = 0; k0 < K; k0 += 32) {
        // stage A: 128 rows x 64B; 2 rounds x 256 lanes x 16B
#pragma unroll
        for (int r = 0; r < 2; r++) {
            int flat = r * 256 + t;
            int arow = row0 + (flat >> 2);
            if (arow > M - 1) arow = M - 1;          // clamp (discarded at store)
            gl_lds16(&A[(size_t)arow * K + k0 + (flat & 3) * 8], &As[flat * 8]);
        }
#pragma unroll
        for (int r = 0; r < 2; r++) {
            int flat = r * 256 + t;
            int brow = col0 + (flat >> 2);           // padded: no clamp needed
            gl_lds16(&Bt[(size_t)brow * K + k0 + (flat & 3) * 8], &Bs[flat * 8]);
        }
        __syncthreads();

        bf16x8 af[4], bfr[4];
#pragma unroll
        for (int i = 0; i < 4; i++)
            af[i] = *(const bf16x8*)&As[(wm + i * 16 + fm) * 32 + fk];
#pragma unroll
        for (int i = 0; i < 4; i++)
            bfr[i] = *(const bf16x8*)&Bs[(wn + i * 16 + fm) * 32 + fk];
#pragma unroll
        for (int i = 0; i < 4; i++)
#pragma unroll
            for (int j = 0; j < 4; j++)
                acc[i][j] = __builtin_amdgcn_mfma_f32_16x16x32_bf16(af[i], bfr[j], acc[i][j], 0, 0, 0);
        __syncthreads();
    }

    // epilogue: C/D layout col=lane&15, row=(lane>>4)*4+reg
    const int crow = row0 + wm + (lane >> 4) * 4;
    const int ccol = col0 + wn + (lane & 15);
#pragma unroll
    for (int j = 0; j < 4; j++) {
        int col = ccol + j * 16;
        if (col < N) {
            float bv = bias ? bias[col] : 0.f;
#pragma unroll
            for (int i = 0; i < 4; i++) {
#pragma unroll
                for (int r2 = 0; r2 < 4; r2++) {
                    int row = crow + i * 16 + r2;
                    if (row < M) {
                        float v = acc[i][j][r2] + bv;
                        if (flags & 1) v = fmaxf(v, 0.f);
                        if (flags & 2) ((bf16*)Cout)[(size_t)row * N + col] = (bf16)v;
                        else           ((float*)Cout)[(size_t)row * N + col] = v;
                    }
                }
            }
        }
    }
}

// ---------------------------------------------------------------------------
// edge aggregation + combine (bf16 in/out, fp32 accumulate):
// H[v] = relu(sum_{e: dst=v} hW[src[e]] + b) + res[v]
// one wave per dst node; lane holds 4 feats.
// ---------------------------------------------------------------------------
__global__ __launch_bounds__(256) void agg_combine_kernel(const bf16* __restrict__ hW,
                                                          const int* __restrict__ csr_src,
                                                          const int* __restrict__ offsets,
                                                          const float* __restrict__ bias,
                                                          const bf16* __restrict__ res,
                                                          bf16* __restrict__ H, int n_nodes) {
    int wave = threadIdx.x >> 6;
    int lane = threadIdx.x & 63;
    int node = blockIdx.x * 4 + wave;
    if (node >= n_nodes) return;
    int beg = offsets[node], end = offsets[node + 1];
    float a0 = 0.f, a1 = 0.f, a2 = 0.f, a3 = 0.f;
    for (int j = beg; j < end; j++) {
        int s = csr_src[j];  // wave-uniform
        bf16x4 v = *(const bf16x4*)&hW[(size_t)s * DD + lane * 4];
        a0 += (float)v[0]; a1 += (float)v[1]; a2 += (float)v[2]; a3 += (float)v[3];
    }
    float4 b = *(const float4*)&bias[lane * 4];
    bf16x4 rv = *(const bf16x4*)&res[(size_t)node * DD + lane * 4];
    bf16x4 o;
    o[0] = (bf16)(fmaxf(a0 + b.x, 0.f) + (float)rv[0]);
    o[1] = (bf16)(fmaxf(a1 + b.y, 0.f) + (float)rv[1]);
    o[2] = (bf16)(fmaxf(a2 + b.z, 0.f) + (float)rv[2]);
    o[3] = (bf16)(fmaxf(a3 + b.w, 0.f) + (float)rv[3]);
    *(bf16x4*)&H[(size_t)node * DD + lane * 4] = o;
}

// ---------------------------------------------------------------------------
// per-graph segment sum of P[N_nodes, GFEAT] (fp32); block per graph
// ---------------------------------------------------------------------------
__global__ __launch_bounds__(256) void graph_reduce_kernel(const float* __restrict__ P,
                                                           const int* __restrict__ gids,
                                                           float* __restrict__ G, int n_nodes) {
    int g = blockIdx.x;
    int lo = 0, hi = n_nodes;
    while (lo < hi) { int mid = (lo + hi) >> 1; if (gids[mid] < g) lo = mid + 1; else hi = mid; }
    int beg = lo;
    hi = n_nodes;
    while (lo < hi) { int mid = (lo + hi) >> 1; if (gids[mid] < g + 1) lo = mid + 1; else hi = mid; }
    int end = lo;

    int c = threadIdx.x;
    if (c < GFEAT) {
        float acc = 0.f;
        for (int r = beg; r < end; r++) acc += P[(size_t)r * GFEAT + c];
        G[(size_t)g * GFEAT + c] = acc;
    }
}

__global__ __launch_bounds__(256) void predictor_kernel(const float* __restrict__ G1,
                                                        const float* __restrict__ G2,
                                                        const float* __restrict__ Wp,
                                                        const float* __restrict__ bp,
                                                        float* __restrict__ out) {
    int i = blockIdx.x * 256 + threadIdx.x;
    if (i >= NG) return;
    float acc = bp[0];
    for (int f = 0; f < GFEAT; f++)
        acc += (G1[i * GFEAT + f] + G2[i * GFEAT + f]) * Wp[f];
    out[i] = acc;
}

// ---------------------------------------------------------------------------
// host-side branch driver
// ---------------------------------------------------------------------------
static void run_branch(const float* X, const int* src, const int* dst, const int* gids,
                       const bf16* Wt, const float* b, const bf16* Wrt, const float* br,
                       const bf16* Rit, const float* rbi, const bf16* Rot, const float* rbo,
                       float* Gout, bf16* Xb, bf16* hWb, bf16* resb, bf16* Hb, float* P,
                       int* offs, int* cursor, int* csr, hipStream_t stream) {
    conv_x_kernel<<<(NN * DD / 4 + 255) / 256, 256, 0, stream>>>(X, Xb, NN * DD / 4);

    zero_ints_kernel<<<(NN + 1 + 255) / 256, 256, 0, stream>>>(offs, NN + 1);
    hist_kernel<<<(NE + 255) / 256, 256, 0, stream>>>(dst, offs, NE);
    scan_kernel<<<1, 1024, 0, stream>>>(offs, cursor, NN);
    scatter_kernel<<<(NE + 255) / 256, 256, 0, stream>>>(src, dst, cursor, csr, NE);

    dim3 g2(2, (NN + 127) / 128);   // N=256 or 200 (Bt padded to 256)
    // hW = X @ W (bf16 out)
    mfma_gemm_kernel<<<g2, 256, 0, stream>>>(Xb, Wt, nullptr, hWb, NN, DD, DD, 2);
    // res = relu(X @ Wr + br) (bf16 out)
    mfma_gemm_kernel<<<g2, 256, 0, stream>>>(Xb, Wrt, br, resb, NN, DD, DD, 3);
    // H = relu(agg + b) + res (bf16)
    agg_combine_kernel<<<(NN + 3) / 4, 256, 0, stream>>>(hWb, csr, offs, b, resb, Hb, NN);
    // R = relu(H @ Ri + rbi) (bf16 out) -> reuse hWb
    mfma_gemm_kernel<<<g2, 256, 0, stream>>>(Hb, Rit, rbi, hWb, NN, DD, DD, 3);
    // P = R @ Ro + rbo (fp32 out, N=200)
    mfma_gemm_kernel<<<g2, 256, 0, stream>>>(hWb, Rot, rbo, P, NN, GFEAT, DD, 0);
    // G = segment_sum(P, gids)
    graph_reduce_kernel<<<NG, 256, 0, stream>>>(P, gids, Gout, NN);
}

extern "C" void kernel_launch(void* const* d_in, const int* in_sizes, int n_in,
                              void* d_out, int out_size, void* d_ws, size_t ws_size,
                              hipStream_t stream) {
    const float* X1   = (const float*)d_in[0];
    const float* X2   = (const float*)d_in[2];
    const int*   src1 = (const int*)d_in[4];
    const int*   dst1 = (const int*)d_in[5];
    const int*   gid1 = (const int*)d_in[6];
    const int*   src2 = (const int*)d_in[7];
    const int*   dst2 = (const int*)d_in[8];
    const int*   gid2 = (const int*)d_in[9];
    const float* W1  = (const float*)d_in[10]; const float* b1  = (const float*)d_in[11];
    const float* Wr1 = (const float*)d_in[12]; const float* br1 = (const float*)d_in[13];
    const float* W2  = (const float*)d_in[14]; const float* b2  = (const float*)d_in[15];
    const float* Wr2 = (const float*)d_in[16]; const float* br2 = (const float*)d_in[17];
    const float* Ri1 = (const float*)d_in[18]; const float* rbi1 = (const float*)d_in[19];
    const float* Ro1 = (const float*)d_in[20]; const float* rbo1 = (const float*)d_in[21];
    const float* Ri2 = (const float*)d_in[22]; const float* rbi2 = (const float*)d_in[23];
    const float* Ro2 = (const float*)d_in[24]; const float* rbo2 = (const float*)d_in[25];
    const float* Wp  = (const float*)d_in[26]; const float* bp  = (const float*)d_in[27];

    // workspace layout
    char* p = (char*)d_ws;
    bf16* Xb   = (bf16*)p; p += (size_t)NN * DD * sizeof(bf16);
    bf16* hWb  = (bf16*)p; p += (size_t)NN * DD * sizeof(bf16);
    bf16* resb = (bf16*)p; p += (size_t)NN * DD * sizeof(bf16);
    bf16* Hb   = (bf16*)p; p += (size_t)NN * DD * sizeof(bf16);
    float* P   = (float*)p; p += (size_t)NN * GFEAT * sizeof(float);
    float* G1  = (float*)p; p += (size_t)NG * GFEAT * sizeof(float);
    float* G2  = (float*)p; p += (size_t)NG * GFEAT * sizeof(float);
    bf16* Wt[8];
    for (int i = 0; i < 8; i++) { Wt[i] = (bf16*)p; p += 256 * 256 * sizeof(bf16); }
    int* offs   = (int*)p; p += (NN + 1) * sizeof(int);
    int* cursor = (int*)p; p += NN * sizeof(int);
    int* csr    = (int*)p;

    // weights -> bf16 transposed [n][k], zero-padded to 256 rows
    conv_w_kernel<<<256, 256, 0, stream>>>(W1,  Wt[0], DD);
    conv_w_kernel<<<256, 256, 0, stream>>>(Wr1, Wt[1], DD);
    conv_w_kernel<<<256, 256, 0, stream>>>(Ri1, Wt[2], DD);
    conv_w_kernel<<<256, 256, 0, stream>>>(Ro1, Wt[3], GFEAT);
    conv_w_kernel<<<256, 256, 0, stream>>>(W2,  Wt[4], DD);
    conv_w_kernel<<<256, 256, 0, stream>>>(Wr2, Wt[5], DD);
    conv_w_kernel<<<256, 256, 0, stream>>>(Ri2, Wt[6], DD);
    conv_w_kernel<<<256, 256, 0, stream>>>(Ro2, Wt[7], GFEAT);

    run_branch(X1, src1, dst1, gid1, Wt[0], b1, Wt[1], br1, Wt[2], rbi1, Wt[3], rbo1,
               G1, Xb, hWb, resb, Hb, P, offs, cursor, csr, stream);
    run_branch(X2, src2, dst2, gid2, Wt[4], b2, Wt[5], br2, Wt[6], rbi2, Wt[7], rbo2,
               G2, Xb, hWb, resb, Hb, P, offs, cursor, csr, stream);

    predictor_kernel<<<(NG + 255) / 256, 256, 0, stream>>>(G1, G2, Wp, bp, (float*)d_out);
}

// Round 3
// 1001.725 us; speedup vs baseline: 1.5966x; 1.1946x over previous
//
#include <hip/hip_runtime.h>

// Problem constants (fixed by reference)
#define NN 50000      // nodes
#define NE 800000     // edges
#define DD 256        // node feat dim
#define GFEAT 200     // graph feat dim
#define NG 512        // graphs

typedef __bf16 bf16;
typedef bf16 bf16x4 __attribute__((ext_vector_type(4)));
typedef bf16 bf16x8 __attribute__((ext_vector_type(8)));
typedef float f32x4 __attribute__((ext_vector_type(4)));

// async global->LDS, 16B per lane. HW dest = wave-uniform base + lane*16.
__device__ __forceinline__ void gl_lds16(const bf16* g, bf16* l) {
    __builtin_amdgcn_global_load_lds(
        (const __attribute__((address_space(1))) uint32_t*)(g),
        (__attribute__((address_space(3))) uint32_t*)(l), 16, 0, 0);
}

// ---------------------------------------------------------------------------
// conversions
// ---------------------------------------------------------------------------
__global__ __launch_bounds__(256) void conv_x_kernel(const float* __restrict__ in,
                                                     bf16* __restrict__ out, int n4) {
    int i = blockIdx.x * 256 + threadIdx.x;
    if (i < n4) {
        float4 v = ((const float4*)in)[i];
        bf16x4 o;
        o[0] = (bf16)v.x; o[1] = (bf16)v.y; o[2] = (bf16)v.z; o[3] = (bf16)v.w;
        ((bf16x4*)out)[i] = o;
    }
}

// in: fp32 [256][N] row-major; out: bf16 [256][256] = [n][k] (transposed, zero-padded)
__global__ __launch_bounds__(256) void conv_w_kernel(const float* __restrict__ in,
                                                     bf16* __restrict__ out, int N) {
    int idx = blockIdx.x * 256 + threadIdx.x;   // 0..65535 over [n][k]
    int n = idx >> 8, k = idx & 255;
    float v = (n < N) ? in[k * N + n] : 0.f;
    out[idx] = (bf16)v;
}

// ---------------------------------------------------------------------------
// CSR build
// ---------------------------------------------------------------------------
__global__ __launch_bounds__(256) void zero_ints_kernel(int* __restrict__ p, int n) {
    int i = blockIdx.x * 256 + threadIdx.x;
    if (i < n) p[i] = 0;
}

__global__ __launch_bounds__(256) void hist_kernel(const int* __restrict__ dst,
                                                   int* __restrict__ counts, int n) {
    int e = blockIdx.x * 256 + threadIdx.x;
    if (e < n) atomicAdd(&counts[dst[e]], 1);
}

// 3-phase multi-block exclusive scan over counts (in place), 1024 elems/block
// Phase A: per-block sums
__global__ __launch_bounds__(256) void block_sum_kernel(const int* __restrict__ counts,
                                                        int* __restrict__ partials, int n) {
    __shared__ int sred[4];
    int base = blockIdx.x * 1024;
    int t = threadIdx.x;
    int sum = 0;
#pragma unroll
    for (int r = 0; r < 4; r++) {
        int idx = base + r * 256 + t;
        if (idx < n) sum += counts[idx];
    }
    for (int off = 32; off > 0; off >>= 1) sum += __shfl_down(sum, off, 64);
    if ((t & 63) == 0) sred[t >> 6] = sum;
    __syncthreads();
    if (t == 0) partials[blockIdx.x] = sred[0] + sred[1] + sred[2] + sred[3];
}

// Phase B: single-wave exclusive scan of nb (<=64) partials; writes total to *total_out
__global__ __launch_bounds__(64) void scan_partials_kernel(int* __restrict__ partials,
                                                           int* __restrict__ total_out, int nb) {
    int t = threadIdx.x;
    int orig = (t < nb) ? partials[t] : 0;
    int v = orig;
#pragma unroll
    for (int off = 1; off < 64; off <<= 1) {
        int u = __shfl_up(v, off, 64);
        if (t >= off) v += u;
    }
    if (t < nb) partials[t] = v - orig;   // exclusive prefix
    if (t == 63) total_out[0] = v;        // grand total
}

// Phase C: per-block local exclusive scan + partial offset; writes offs & cursor
__global__ __launch_bounds__(256) void scan_apply_kernel(int* __restrict__ offs /*counts in*/,
                                                         const int* __restrict__ partials,
                                                         int* __restrict__ cursor, int n) {
    __shared__ int ts[256];
    int base = blockIdx.x * 1024;
    int t = threadIdx.x;
    int c[4];
    int sum = 0;
#pragma unroll
    for (int r = 0; r < 4; r++) {
        int idx = base + t * 4 + r;
        c[r] = (idx < n) ? offs[idx] : 0;
        sum += c[r];
    }
    ts[t] = sum;
    __syncthreads();
    for (int off = 1; off < 256; off <<= 1) {
        int v = (t >= off) ? ts[t - off] : 0;
        __syncthreads();
        ts[t] += v;
        __syncthreads();
    }
    int run = partials[blockIdx.x] + ts[t] - sum;
#pragma unroll
    for (int r = 0; r < 4; r++) {
        int idx = base + t * 4 + r;
        if (idx < n) { offs[idx] = run; cursor[idx] = run; run += c[r]; }
    }
}

__global__ __launch_bounds__(256) void scatter_kernel(const int* __restrict__ src,
                                                      const int* __restrict__ dst,
                                                      int* __restrict__ cursor,
                                                      int* __restrict__ csr, int n) {
    int e = blockIdx.x * 256 + threadIdx.x;
    if (e < n) {
        int pos = atomicAdd(&cursor[dst[e]], 1);
        csr[pos] = src[e];
    }
}

// ---------------------------------------------------------------------------
// bf16 MFMA GEMM: C[M,N] = A[M,K] @ Bt[N,K]^T (+bias) (+relu)
// 128x128 tile, BK=32, 256 threads (4 waves, 2x2), 4x4 16x16x32 MFMAs per wave.
// Bt must be padded to gridDim.x*128 rows. flags: bit0 = relu, bit1 = bf16 out.
// ---------------------------------------------------------------------------
__global__ __launch_bounds__(256) void mfma_gemm_kernel(
    const bf16* __restrict__ A, const bf16* __restrict__ Bt,
    const float* __restrict__ bias, void* __restrict__ Cout,
    int M, int N, int K, int flags) {
    __shared__ bf16 As[128 * 32];   // [m][k]
    __shared__ bf16 Bs[128 * 32];   // [n][k]

    const int t    = threadIdx.x;
    const int lane = t & 63;
    const int w    = t >> 6;
    const int row0 = blockIdx.y * 128;
    const int col0 = blockIdx.x * 128;

    f32x4 acc[4][4] = {};

    const int wm = (w >> 1) * 64, wn = (w & 1) * 64;
    const int fm = lane & 15, fk = (lane >> 4) * 8;

    for (int k0 = 0; k0 < K; k0 += 32) {
#pragma unroll
        for (int r = 0; r < 2; r++) {
            int flat = r * 256 + t;
            int arow = row0 + (flat >> 2);
            if (arow > M - 1) arow = M - 1;          // clamp (discarded at store)
            gl_lds16(&A[(size_t)arow * K + k0 + (flat & 3) * 8], &As[flat * 8]);
        }
#pragma unroll
        for (int r = 0; r < 2; r++) {
            int flat = r * 256 + t;
            int brow = col0 + (flat >> 2);           // padded: no clamp needed
            gl_lds16(&Bt[(size_t)brow * K + k0 + (flat & 3) * 8], &Bs[flat * 8]);
        }
        __syncthreads();

        bf16x8 af[4], bfr[4];
#pragma unroll
        for (int i = 0; i < 4; i++)
            af[i] = *(const bf16x8*)&As[(wm + i * 16 + fm) * 32 + fk];
#pragma unroll
        for (int i = 0; i < 4; i++)
            bfr[i] = *(const bf16x8*)&Bs[(wn + i * 16 + fm) * 32 + fk];
#pragma unroll
        for (int i = 0; i < 4; i++)
#pragma unroll
            for (int j = 0; j < 4; j++)
                acc[i][j] = __builtin_amdgcn_mfma_f32_16x16x32_bf16(af[i], bfr[j], acc[i][j], 0, 0, 0);
        __syncthreads();
    }

    // epilogue: C/D layout col=lane&15, row=(lane>>4)*4+reg
    const int crow = row0 + wm + (lane >> 4) * 4;
    const int ccol = col0 + wn + (lane & 15);
#pragma unroll
    for (int j = 0; j < 4; j++) {
        int col = ccol + j * 16;
        if (col < N) {
            float bv = bias ? bias[col] : 0.f;
#pragma unroll
            for (int i = 0; i < 4; i++) {
#pragma unroll
                for (int r2 = 0; r2 < 4; r2++) {
                    int row = crow + i * 16 + r2;
                    if (row < M) {
                        float v = acc[i][j][r2] + bv;
                        if (flags & 1) v = fmaxf(v, 0.f);
                        if (flags & 2) ((bf16*)Cout)[(size_t)row * N + col] = (bf16)v;
                        else           ((float*)Cout)[(size_t)row * N + col] = v;
                    }
                }
            }
        }
    }
}

// ---------------------------------------------------------------------------
// edge aggregation + combine (bf16 in/out, fp32 accumulate):
// H[v] = relu(sum_{e: dst=v} hW[src[e]] + b) + res[v]
// one wave per dst node; lane holds 4 feats.
// ---------------------------------------------------------------------------
__global__ __launch_bounds__(256) void agg_combine_kernel(const bf16* __restrict__ hW,
                                                          const int* __restrict__ csr_src,
                                                          const int* __restrict__ offsets,
                                                          const float* __restrict__ bias,
                                                          const bf16* __restrict__ res,
                                                          bf16* __restrict__ H, int n_nodes) {
    int wave = threadIdx.x >> 6;
    int lane = threadIdx.x & 63;
    int node = blockIdx.x * 4 + wave;
    if (node >= n_nodes) return;
    int beg = offsets[node], end = offsets[node + 1];
    float a0 = 0.f, a1 = 0.f, a2 = 0.f, a3 = 0.f;
    for (int j = beg; j < end; j++) {
        int s = csr_src[j];  // wave-uniform
        bf16x4 v = *(const bf16x4*)&hW[(size_t)s * DD + lane * 4];
        a0 += (float)v[0]; a1 += (float)v[1]; a2 += (float)v[2]; a3 += (float)v[3];
    }
    float4 b = *(const float4*)&bias[lane * 4];
    bf16x4 rv = *(const bf16x4*)&res[(size_t)node * DD + lane * 4];
    bf16x4 o;
    o[0] = (bf16)(fmaxf(a0 + b.x, 0.f) + (float)rv[0]);
    o[1] = (bf16)(fmaxf(a1 + b.y, 0.f) + (float)rv[1]);
    o[2] = (bf16)(fmaxf(a2 + b.z, 0.f) + (float)rv[2]);
    o[3] = (bf16)(fmaxf(a3 + b.w, 0.f) + (float)rv[3]);
    *(bf16x4*)&H[(size_t)node * DD + lane * 4] = o;
}

// ---------------------------------------------------------------------------
// per-graph segment sum of P[N_nodes, GFEAT] (fp32); block per graph
// ---------------------------------------------------------------------------
__global__ __launch_bounds__(256) void graph_reduce_kernel(const float* __restrict__ P,
                                                           const int* __restrict__ gids,
                                                           float* __restrict__ G, int n_nodes) {
    int g = blockIdx.x;
    int lo = 0, hi = n_nodes;
    while (lo < hi) { int mid = (lo + hi) >> 1; if (gids[mid] < g) lo = mid + 1; else hi = mid; }
    int beg = lo;
    hi = n_nodes;
    while (lo < hi) { int mid = (lo + hi) >> 1; if (gids[mid] < g + 1) lo = mid + 1; else hi = mid; }
    int end = lo;

    int c = threadIdx.x;
    if (c < GFEAT) {
        float acc = 0.f;
        for (int r = beg; r < end; r++) acc += P[(size_t)r * GFEAT + c];
        G[(size_t)g * GFEAT + c] = acc;
    }
}

__global__ __launch_bounds__(256) void predictor_kernel(const float* __restrict__ G1,
                                                        const float* __restrict__ G2,
                                                        const float* __restrict__ Wp,
                                                        const float* __restrict__ bp,
                                                        float* __restrict__ out) {
    int i = blockIdx.x * 256 + threadIdx.x;
    if (i >= NG) return;
    float acc = bp[0];
    for (int f = 0; f < GFEAT; f++)
        acc += (G1[i * GFEAT + f] + G2[i * GFEAT + f]) * Wp[f];
    out[i] = acc;
}

// ---------------------------------------------------------------------------
// host-side branch driver
// ---------------------------------------------------------------------------
static void run_branch(const float* X, const int* src, const int* dst, const int* gids,
                       const bf16* Wt, const float* b, const bf16* Wrt, const float* br,
                       const bf16* Rit, const float* rbi, const bf16* Rot, const float* rbo,
                       float* Gout, bf16* Xb, bf16* hWb, bf16* resb, bf16* Hb, float* P,
                       int* offs, int* partials, int* cursor, int* csr, hipStream_t stream) {
    conv_x_kernel<<<(NN * DD / 4 + 255) / 256, 256, 0, stream>>>(X, Xb, NN * DD / 4);

    const int NB = (NN + 1023) / 1024;   // 49
    zero_ints_kernel<<<(NN + 1 + 255) / 256, 256, 0, stream>>>(offs, NN + 1);
    hist_kernel<<<(NE + 255) / 256, 256, 0, stream>>>(dst, offs, NE);
    block_sum_kernel<<<NB, 256, 0, stream>>>(offs, partials, NN);
    scan_partials_kernel<<<1, 64, 0, stream>>>(partials, &offs[NN], NB);
    scan_apply_kernel<<<NB, 256, 0, stream>>>(offs, partials, cursor, NN);
    scatter_kernel<<<(NE + 255) / 256, 256, 0, stream>>>(src, dst, cursor, csr, NE);

    dim3 g2(2, (NN + 127) / 128);   // N=256 or 200 (Bt padded to 256)
    // hW = X @ W (bf16 out)
    mfma_gemm_kernel<<<g2, 256, 0, stream>>>(Xb, Wt, nullptr, hWb, NN, DD, DD, 2);
    // res = relu(X @ Wr + br) (bf16 out)
    mfma_gemm_kernel<<<g2, 256, 0, stream>>>(Xb, Wrt, br, resb, NN, DD, DD, 3);
    // H = relu(agg + b) + res (bf16)
    agg_combine_kernel<<<(NN + 3) / 4, 256, 0, stream>>>(hWb, csr, offs, b, resb, Hb, NN);
    // R = relu(H @ Ri + rbi) (bf16 out) -> reuse hWb
    mfma_gemm_kernel<<<g2, 256, 0, stream>>>(Hb, Rit, rbi, hWb, NN, DD, DD, 3);
    // P = R @ Ro + rbo (fp32 out, N=200)
    mfma_gemm_kernel<<<g2, 256, 0, stream>>>(hWb, Rot, rbo, P, NN, GFEAT, DD, 0);
    // G = segment_sum(P, gids)
    graph_reduce_kernel<<<NG, 256, 0, stream>>>(P, gids, Gout, NN);
}

extern "C" void kernel_launch(void* const* d_in, const int* in_sizes, int n_in,
                              void* d_out, int out_size, void* d_ws, size_t ws_size,
                              hipStream_t stream) {
    const float* X1   = (const float*)d_in[0];
    const float* X2   = (const float*)d_in[2];
    const int*   src1 = (const int*)d_in[4];
    const int*   dst1 = (const int*)d_in[5];
    const int*   gid1 = (const int*)d_in[6];
    const int*   src2 = (const int*)d_in[7];
    const int*   dst2 = (const int*)d_in[8];
    const int*   gid2 = (const int*)d_in[9];
    const float* W1  = (const float*)d_in[10]; const float* b1  = (const float*)d_in[11];
    const float* Wr1 = (const float*)d_in[12]; const float* br1 = (const float*)d_in[13];
    const float* W2  = (const float*)d_in[14]; const float* b2  = (const float*)d_in[15];
    const float* Wr2 = (const float*)d_in[16]; const float* br2 = (const float*)d_in[17];
    const float* Ri1 = (const float*)d_in[18]; const float* rbi1 = (const float*)d_in[19];
    const float* Ro1 = (const float*)d_in[20]; const float* rbo1 = (const float*)d_in[21];
    const float* Ri2 = (const float*)d_in[22]; const float* rbi2 = (const float*)d_in[23];
    const float* Ro2 = (const float*)d_in[24]; const float* rbo2 = (const float*)d_in[25];
    const float* Wp  = (const float*)d_in[26]; const float* bp  = (const float*)d_in[27];

    // workspace layout
    char* p = (char*)d_ws;
    bf16* Xb   = (bf16*)p; p += (size_t)NN * DD * sizeof(bf16);
    bf16* hWb  = (bf16*)p; p += (size_t)NN * DD * sizeof(bf16);
    bf16* resb = (bf16*)p; p += (size_t)NN * DD * sizeof(bf16);
    bf16* Hb   = (bf16*)p; p += (size_t)NN * DD * sizeof(bf16);
    float* P   = (float*)p; p += (size_t)NN * GFEAT * sizeof(float);
    float* G1  = (float*)p; p += (size_t)NG * GFEAT * sizeof(float);
    float* G2  = (float*)p; p += (size_t)NG * GFEAT * sizeof(float);
    bf16* Wt[8];
    for (int i = 0; i < 8; i++) { Wt[i] = (bf16*)p; p += 256 * 256 * sizeof(bf16); }
    int* offs     = (int*)p; p += (NN + 1) * sizeof(int);
    int* partials = (int*)p; p += 64 * sizeof(int);
    int* cursor   = (int*)p; p += NN * sizeof(int);
    int* csr      = (int*)p;

    // weights -> bf16 transposed [n][k], zero-padded to 256 rows
    conv_w_kernel<<<256, 256, 0, stream>>>(W1,  Wt[0], DD);
    conv_w_kernel<<<256, 256, 0, stream>>>(Wr1, Wt[1], DD);
    conv_w_kernel<<<256, 256, 0, stream>>>(Ri1, Wt[2], DD);
    conv_w_kernel<<<256, 256, 0, stream>>>(Ro1, Wt[3], GFEAT);
    conv_w_kernel<<<256, 256, 0, stream>>>(W2,  Wt[4], DD);
    conv_w_kernel<<<256, 256, 0, stream>>>(Wr2, Wt[5], DD);
    conv_w_kernel<<<256, 256, 0, stream>>>(Ri2, Wt[6], DD);
    conv_w_kernel<<<256, 256, 0, stream>>>(Ro2, Wt[7], GFEAT);

    run_branch(X1, src1, dst1, gid1, Wt[0], b1, Wt[1], br1, Wt[2], rbi1, Wt[3], rbo1,
               G1, Xb, hWb, resb, Hb, P, offs, partials, cursor, csr, stream);
    run_branch(X2, src2, dst2, gid2, Wt[4], b2, Wt[5], br2, Wt[6], rbi2, Wt[7], rbo2,
               G2, Xb, hWb, resb, Hb, P, offs, partials, cursor, csr, stream);

    predictor_kernel<<<(NG + 255) / 256, 256, 0, stream>>>(G1, G2, Wp, bp, (float*)d_out);
}

// Round 4
// 887.977 us; speedup vs baseline: 1.8011x; 1.1281x over previous
//
#include <hip/hip_runtime.h>

// Problem constants (fixed by reference)
#define NN 50000      // nodes
#define NE 800000     // edges
#define DD 256        // node feat dim
#define GFEAT 200     // graph feat dim
#define NG 512        // graphs

typedef __bf16 bf16;
typedef bf16 bf16x4 __attribute__((ext_vector_type(4)));
typedef bf16 bf16x8 __attribute__((ext_vector_type(8)));
typedef float f32x4 __attribute__((ext_vector_type(4)));

// async global->LDS, 16B per lane. HW dest = wave-uniform base + lane*16.
__device__ __forceinline__ void gl_lds16(const bf16* g, bf16* l) {
    __builtin_amdgcn_global_load_lds(
        (const __attribute__((address_space(1))) uint32_t*)(g),
        (__attribute__((address_space(3))) uint32_t*)(l), 16, 0, 0);
}

// ---------------------------------------------------------------------------
// conversions
// ---------------------------------------------------------------------------
// X (fp32) -> bf16, two matrices in one launch (blockIdx.y selects)
__global__ __launch_bounds__(256) void conv_x2_kernel(const float* __restrict__ in0,
                                                      const float* __restrict__ in1,
                                                      bf16* __restrict__ out0,
                                                      bf16* __restrict__ out1, int n4) {
    const float* in = blockIdx.y ? in1 : in0;
    bf16* out = blockIdx.y ? out1 : out0;
    int i = blockIdx.x * 256 + threadIdx.x;
    if (i < n4) {
        float4 v = ((const float4*)in)[i];
        bf16x4 o;
        o[0] = (bf16)v.x; o[1] = (bf16)v.y; o[2] = (bf16)v.z; o[3] = (bf16)v.w;
        ((bf16x4*)out)[i] = o;
    }
}

// 8 weight matrices fp32 [K][N] -> bf16 [256][256] = [n][k] transposed, zero-padded.
// grid (256, 8); out[m] = base + m*65536.
__global__ __launch_bounds__(256) void conv_w8_kernel(
    const float* __restrict__ w0, const float* __restrict__ w1,
    const float* __restrict__ w2, const float* __restrict__ w3,
    const float* __restrict__ w4, const float* __restrict__ w5,
    const float* __restrict__ w6, const float* __restrict__ w7,
    bf16* __restrict__ out_base) {
    const float* ws[8] = {w0, w1, w2, w3, w4, w5, w6, w7};
    const int Ns[8] = {DD, DD, DD, GFEAT, DD, DD, DD, GFEAT};
    int m = blockIdx.y;
    const float* in = ws[m];
    int N = Ns[m];
    int idx = blockIdx.x * 256 + threadIdx.x;   // 0..65535 over [n][k]
    int n = idx >> 8, k = idx & 255;
    float v = (n < N) ? in[k * N + n] : 0.f;
    out_base[(size_t)m * 65536 + idx] = (bf16)v;
}

// ---------------------------------------------------------------------------
// CSR build
// ---------------------------------------------------------------------------
__global__ __launch_bounds__(256) void zero_ints_kernel(int* __restrict__ p, int n) {
    int i = blockIdx.x * 256 + threadIdx.x;
    if (i < n) p[i] = 0;
}

__global__ __launch_bounds__(256) void hist_kernel(const int* __restrict__ dst,
                                                   int* __restrict__ counts, int n) {
    int e = blockIdx.x * 256 + threadIdx.x;
    if (e < n) atomicAdd(&counts[dst[e]], 1);
}

// Phase A: per-block sums (1024 elems/block)
__global__ __launch_bounds__(256) void block_sum_kernel(const int* __restrict__ counts,
                                                        int* __restrict__ partials, int n) {
    __shared__ int sred[4];
    int base = blockIdx.x * 1024;
    int t = threadIdx.x;
    int sum = 0;
#pragma unroll
    for (int r = 0; r < 4; r++) {
        int idx = base + r * 256 + t;
        if (idx < n) sum += counts[idx];
    }
    for (int off = 32; off > 0; off >>= 1) sum += __shfl_down(sum, off, 64);
    if ((t & 63) == 0) sred[t >> 6] = sum;
    __syncthreads();
    if (t == 0) partials[blockIdx.x] = sred[0] + sred[1] + sred[2] + sred[3];
}

// Phase B: single-wave exclusive scan of nb (<=64) partials
__global__ __launch_bounds__(64) void scan_partials_kernel(int* __restrict__ partials,
                                                           int* __restrict__ total_out, int nb) {
    int t = threadIdx.x;
    int orig = (t < nb) ? partials[t] : 0;
    int v = orig;
#pragma unroll
    for (int off = 1; off < 64; off <<= 1) {
        int u = __shfl_up(v, off, 64);
        if (t >= off) v += u;
    }
    if (t < nb) partials[t] = v - orig;   // exclusive prefix
    if (t == 63) total_out[0] = v;        // grand total
}

// Phase C: per-block local exclusive scan + partial offset
__global__ __launch_bounds__(256) void scan_apply_kernel(int* __restrict__ offs,
                                                         const int* __restrict__ partials,
                                                         int* __restrict__ cursor, int n) {
    __shared__ int ts[256];
    int base = blockIdx.x * 1024;
    int t = threadIdx.x;
    int c[4];
    int sum = 0;
#pragma unroll
    for (int r = 0; r < 4; r++) {
        int idx = base + t * 4 + r;
        c[r] = (idx < n) ? offs[idx] : 0;
        sum += c[r];
    }
    ts[t] = sum;
    __syncthreads();
    for (int off = 1; off < 256; off <<= 1) {
        int v = (t >= off) ? ts[t - off] : 0;
        __syncthreads();
        ts[t] += v;
        __syncthreads();
    }
    int run = partials[blockIdx.x] + ts[t] - sum;
#pragma unroll
    for (int r = 0; r < 4; r++) {
        int idx = base + t * 4 + r;
        if (idx < n) { offs[idx] = run; cursor[idx] = run; run += c[r]; }
    }
}

__global__ __launch_bounds__(256) void scatter_kernel(const int* __restrict__ src,
                                                      const int* __restrict__ dst,
                                                      int* __restrict__ cursor,
                                                      int* __restrict__ csr, int n) {
    int e = blockIdx.x * 256 + threadIdx.x;
    if (e < n) {
        int pos = atomicAdd(&cursor[dst[e]], 1);
        csr[pos] = src[e];
    }
}

// ---------------------------------------------------------------------------
// bf16 MFMA GEMM: C[M,N] = A[M,K] @ Bt[N,K]^T (+bias) (+relu)
// 128x128 tile, BK=32, 256 threads (4 waves, 2x2), 4x4 16x16x32 MFMAs per wave.
// Bt padded to gridDim.x*128 rows. flags: bit0 = relu, bit1 = bf16 out.
// ---------------------------------------------------------------------------
__global__ __launch_bounds__(256) void mfma_gemm_kernel(
    const bf16* __restrict__ A, const bf16* __restrict__ Bt,
    const float* __restrict__ bias, void* __restrict__ Cout,
    int M, int N, int K, int flags) {
    __shared__ bf16 As[128 * 32];   // [m][k]
    __shared__ bf16 Bs[128 * 32];   // [n][k]

    const int t    = threadIdx.x;
    const int lane = t & 63;
    const int w    = t >> 6;
    const int row0 = blockIdx.y * 128;
    const int col0 = blockIdx.x * 128;

    f32x4 acc[4][4] = {};

    const int wm = (w >> 1) * 64, wn = (w & 1) * 64;
    const int fm = lane & 15, fk = (lane >> 4) * 8;

    for (int k0 = 0; k0 < K; k0 += 32) {
#pragma unroll
        for (int r = 0; r < 2; r++) {
            int flat = r * 256 + t;
            int arow = row0 + (flat >> 2);
            if (arow > M - 1) arow = M - 1;          // clamp (discarded at store)
            gl_lds16(&A[(size_t)arow * K + k0 + (flat & 3) * 8], &As[flat * 8]);
        }
#pragma unroll
        for (int r = 0; r < 2; r++) {
            int flat = r * 256 + t;
            int brow = col0 + (flat >> 2);           // padded: no clamp needed
            gl_lds16(&Bt[(size_t)brow * K + k0 + (flat & 3) * 8], &Bs[flat * 8]);
        }
        __syncthreads();

        bf16x8 af[4], bfr[4];
#pragma unroll
        for (int i = 0; i < 4; i++)
            af[i] = *(const bf16x8*)&As[(wm + i * 16 + fm) * 32 + fk];
#pragma unroll
        for (int i = 0; i < 4; i++)
            bfr[i] = *(const bf16x8*)&Bs[(wn + i * 16 + fm) * 32 + fk];
#pragma unroll
        for (int i = 0; i < 4; i++)
#pragma unroll
            for (int j = 0; j < 4; j++)
                acc[i][j] = __builtin_amdgcn_mfma_f32_16x16x32_bf16(af[i], bfr[j], acc[i][j], 0, 0, 0);
        __syncthreads();
    }

    const int crow = row0 + wm + (lane >> 4) * 4;
    const int ccol = col0 + wn + (lane & 15);
#pragma unroll
    for (int j = 0; j < 4; j++) {
        int col = ccol + j * 16;
        if (col < N) {
            float bv = bias ? bias[col] : 0.f;
#pragma unroll
            for (int i = 0; i < 4; i++) {
#pragma unroll
                for (int r2 = 0; r2 < 4; r2++) {
                    int row = crow + i * 16 + r2;
                    if (row < M) {
                        float v = acc[i][j][r2] + bv;
                        if (flags & 1) v = fmaxf(v, 0.f);
                        if (flags & 2) ((bf16*)Cout)[(size_t)row * N + col] = (bf16)v;
                        else           ((float*)Cout)[(size_t)row * N + col] = v;
                    }
                }
            }
        }
    }
}

// Fused W+Wr GEMM: Bt2 is 512x256 (rows 0-255 = Wt, 256-511 = Wrt).
// cols 0-255 -> out_lo (hW, no act), cols 256-511 -> out_hi = relu(.+bias_hi) (res).
// grid (4, ceil(M/128)).
__global__ __launch_bounds__(256) void mfma_gemm_fused_kernel(
    const bf16* __restrict__ A, const bf16* __restrict__ Bt2,
    const float* __restrict__ bias_hi,
    bf16* __restrict__ out_lo, bf16* __restrict__ out_hi, int M) {
    __shared__ bf16 As[128 * 32];
    __shared__ bf16 Bs[128 * 32];

    const int t    = threadIdx.x;
    const int lane = t & 63;
    const int w    = t >> 6;
    const int row0 = blockIdx.y * 128;
    const int col0 = blockIdx.x * 128;   // 0..384

    f32x4 acc[4][4] = {};
    const int wm = (w >> 1) * 64, wn = (w & 1) * 64;
    const int fm = lane & 15, fk = (lane >> 4) * 8;

    for (int k0 = 0; k0 < 256; k0 += 32) {
#pragma unroll
        for (int r = 0; r < 2; r++) {
            int flat = r * 256 + t;
            int arow = row0 + (flat >> 2);
            if (arow > M - 1) arow = M - 1;
            gl_lds16(&A[(size_t)arow * 256 + k0 + (flat & 3) * 8], &As[flat * 8]);
        }
#pragma unroll
        for (int r = 0; r < 2; r++) {
            int flat = r * 256 + t;
            int brow = col0 + (flat >> 2);
            gl_lds16(&Bt2[(size_t)brow * 256 + k0 + (flat & 3) * 8], &Bs[flat * 8]);
        }
        __syncthreads();

        bf16x8 af[4], bfr[4];
#pragma unroll
        for (int i = 0; i < 4; i++)
            af[i] = *(const bf16x8*)&As[(wm + i * 16 + fm) * 32 + fk];
#pragma unroll
        for (int i = 0; i < 4; i++)
            bfr[i] = *(const bf16x8*)&Bs[(wn + i * 16 + fm) * 32 + fk];
#pragma unroll
        for (int i = 0; i < 4; i++)
#pragma unroll
            for (int j = 0; j < 4; j++)
                acc[i][j] = __builtin_amdgcn_mfma_f32_16x16x32_bf16(af[i], bfr[j], acc[i][j], 0, 0, 0);
        __syncthreads();
    }

    const bool hi = (col0 >= 256);          // block-uniform
    bf16* out = hi ? out_hi : out_lo;
    const int cb = hi ? col0 - 256 : col0;
    const int crow = row0 + wm + (lane >> 4) * 4;
    const int ccol = cb + wn + (lane & 15);
#pragma unroll
    for (int j = 0; j < 4; j++) {
        int col = ccol + j * 16;
        float bv = hi ? bias_hi[col] : 0.f;
#pragma unroll
        for (int i = 0; i < 4; i++) {
#pragma unroll
            for (int r2 = 0; r2 < 4; r2++) {
                int row = crow + i * 16 + r2;
                if (row < M) {
                    float v = acc[i][j][r2] + bv;
                    if (hi) v = fmaxf(v, 0.f);
                    out[(size_t)row * 256 + col] = (bf16)v;
                }
            }
        }
    }
}

// ---------------------------------------------------------------------------
// edge aggregation + combine (bf16 in/out, fp32 accumulate):
// H[v] = relu(sum_{e: dst=v} hW[src[e]] + b) + res[v]
// one wave per dst node; lane covers 8 feats (16B), half-waves cover 2 edges.
// ---------------------------------------------------------------------------
__global__ __launch_bounds__(256) void agg_combine_kernel(const bf16* __restrict__ hW,
                                                          const int* __restrict__ csr_src,
                                                          const int* __restrict__ offsets,
                                                          const float* __restrict__ bias,
                                                          const bf16* __restrict__ res,
                                                          bf16* __restrict__ H, int n_nodes) {
    int wave = threadIdx.x >> 6;
    int lane = threadIdx.x & 63;
    int node = blockIdx.x * 4 + wave;
    if (node >= n_nodes) return;
    int beg = offsets[node], end = offsets[node + 1];
    const int half = lane >> 5;          // which edge of the pair
    const int fo   = (lane & 31) * 8;    // feature offset (8 feats = 16 B)

    float acc[8] = {};
    int j = beg;
    // 4 gathers in flight: 2 edges x unroll 2
    for (; j + 2 + half < end; j += 4) {
        int s0 = csr_src[j + half];
        int s1 = csr_src[j + 2 + half];
        bf16x8 v0 = *(const bf16x8*)&hW[(size_t)s0 * DD + fo];
        bf16x8 v1 = *(const bf16x8*)&hW[(size_t)s1 * DD + fo];
#pragma unroll
        for (int q = 0; q < 8; q++) acc[q] += (float)v0[q];
#pragma unroll
        for (int q = 0; q < 8; q++) acc[q] += (float)v1[q];
    }
    for (; j + half < end; j += 2) {
        int s = csr_src[j + half];
        bf16x8 v = *(const bf16x8*)&hW[(size_t)s * DD + fo];
#pragma unroll
        for (int q = 0; q < 8; q++) acc[q] += (float)v[q];
    }
    // merge the two half-wave edge subsets (lanes l and l^32 hold same feats)
#pragma unroll
    for (int q = 0; q < 8; q++) acc[q] += __shfl_xor(acc[q], 32, 64);

    if (half == 0) {
        float4 b0 = *(const float4*)&bias[fo];
        float4 b1 = *(const float4*)&bias[fo + 4];
        bf16x8 rv = *(const bf16x8*)&res[(size_t)node * DD + fo];
        bf16x8 o;
        o[0] = (bf16)(fmaxf(acc[0] + b0.x, 0.f) + (float)rv[0]);
        o[1] = (bf16)(fmaxf(acc[1] + b0.y, 0.f) + (float)rv[1]);
        o[2] = (bf16)(fmaxf(acc[2] + b0.z, 0.f) + (float)rv[2]);
        o[3] = (bf16)(fmaxf(acc[3] + b0.w, 0.f) + (float)rv[3]);
        o[4] = (bf16)(fmaxf(acc[4] + b1.x, 0.f) + (float)rv[4]);
        o[5] = (bf16)(fmaxf(acc[5] + b1.y, 0.f) + (float)rv[5]);
        o[6] = (bf16)(fmaxf(acc[6] + b1.z, 0.f) + (float)rv[6]);
        o[7] = (bf16)(fmaxf(acc[7] + b1.w, 0.f) + (float)rv[7]);
        *(bf16x8*)&H[(size_t)node * DD + fo] = o;
    }
}

// ---------------------------------------------------------------------------
// per-graph segment sum of P[N_nodes, GFEAT] (fp32); block per graph
// ---------------------------------------------------------------------------
__global__ __launch_bounds__(256) void graph_reduce_kernel(const float* __restrict__ P,
                                                           const int* __restrict__ gids,
                                                           float* __restrict__ G, int n_nodes) {
    int g = blockIdx.x;
    int lo = 0, hi = n_nodes;
    while (lo < hi) { int mid = (lo + hi) >> 1; if (gids[mid] < g) lo = mid + 1; else hi = mid; }
    int beg = lo;
    hi = n_nodes;
    while (lo < hi) { int mid = (lo + hi) >> 1; if (gids[mid] < g + 1) lo = mid + 1; else hi = mid; }
    int end = lo;

    int c = threadIdx.x;
    if (c < GFEAT) {
        float acc = 0.f;
        for (int r = beg; r < end; r++) acc += P[(size_t)r * GFEAT + c];
        G[(size_t)g * GFEAT + c] = acc;
    }
}

__global__ __launch_bounds__(256) void predictor_kernel(const float* __restrict__ G1,
                                                        const float* __restrict__ G2,
                                                        const float* __restrict__ Wp,
                                                        const float* __restrict__ bp,
                                                        float* __restrict__ out) {
    int i = blockIdx.x * 256 + threadIdx.x;
    if (i >= NG) return;
    float acc = bp[0];
    for (int f = 0; f < GFEAT; f++)
        acc += (G1[i * GFEAT + f] + G2[i * GFEAT + f]) * Wp[f];
    out[i] = acc;
}

// ---------------------------------------------------------------------------
// host-side branch driver
// ---------------------------------------------------------------------------
static void run_branch(const bf16* Xb, const int* src, const int* dst, const int* gids,
                       const bf16* WWr, const float* b, const float* br,
                       const bf16* Rit, const float* rbi, const bf16* Rot, const float* rbo,
                       float* Gout, bf16* hWb, bf16* resb, bf16* Hb, float* P,
                       int* offs, int* partials, int* cursor, int* csr, hipStream_t stream) {
    const int NB = (NN + 1023) / 1024;   // 49
    zero_ints_kernel<<<(NN + 1 + 255) / 256, 256, 0, stream>>>(offs, NN + 1);
    hist_kernel<<<(NE + 255) / 256, 256, 0, stream>>>(dst, offs, NE);
    block_sum_kernel<<<NB, 256, 0, stream>>>(offs, partials, NN);
    scan_partials_kernel<<<1, 64, 0, stream>>>(partials, &offs[NN], NB);
    scan_apply_kernel<<<NB, 256, 0, stream>>>(offs, partials, cursor, NN);
    scatter_kernel<<<(NE + 255) / 256, 256, 0, stream>>>(src, dst, cursor, csr, NE);

    dim3 gf(4, (NN + 127) / 128);
    dim3 g2(2, (NN + 127) / 128);
    // hW = X @ W ; res = relu(X @ Wr + br)   (fused, bf16 out)
    mfma_gemm_fused_kernel<<<gf, 256, 0, stream>>>(Xb, WWr, br, hWb, resb, NN);
    // H = relu(agg + b) + res (bf16)
    agg_combine_kernel<<<(NN + 3) / 4, 256, 0, stream>>>(hWb, csr, offs, b, resb, Hb, NN);
    // R = relu(H @ Ri + rbi) (bf16 out) -> reuse hWb
    mfma_gemm_kernel<<<g2, 256, 0, stream>>>(Hb, Rit, rbi, hWb, NN, DD, DD, 3);
    // P = R @ Ro + rbo (fp32 out, N=200)
    mfma_gemm_kernel<<<g2, 256, 0, stream>>>(hWb, Rot, rbo, P, NN, GFEAT, DD, 0);
    // G = segment_sum(P, gids)
    graph_reduce_kernel<<<NG, 256, 0, stream>>>(P, gids, Gout, NN);
}

extern "C" void kernel_launch(void* const* d_in, const int* in_sizes, int n_in,
                              void* d_out, int out_size, void* d_ws, size_t ws_size,
                              hipStream_t stream) {
    const float* X1   = (const float*)d_in[0];
    const float* X2   = (const float*)d_in[2];
    const int*   src1 = (const int*)d_in[4];
    const int*   dst1 = (const int*)d_in[5];
    const int*   gid1 = (const int*)d_in[6];
    const int*   src2 = (const int*)d_in[7];
    const int*   dst2 = (const int*)d_in[8];
    const int*   gid2 = (const int*)d_in[9];
    const float* W1  = (const float*)d_in[10]; const float* b1  = (const float*)d_in[11];
    const float* Wr1 = (const float*)d_in[12]; const float* br1 = (const float*)d_in[13];
    const float* W2  = (const float*)d_in[14]; const float* b2  = (const float*)d_in[15];
    const float* Wr2 = (const float*)d_in[16]; const float* br2 = (const float*)d_in[17];
    const float* Ri1 = (const float*)d_in[18]; const float* rbi1 = (const float*)d_in[19];
    const float* Ro1 = (const float*)d_in[20]; const float* rbo1 = (const float*)d_in[21];
    const float* Ri2 = (const float*)d_in[22]; const float* rbi2 = (const float*)d_in[23];
    const float* Ro2 = (const float*)d_in[24]; const float* rbo2 = (const float*)d_in[25];
    const float* Wp  = (const float*)d_in[26]; const float* bp  = (const float*)d_in[27];

    // workspace layout
    char* p = (char*)d_ws;
    bf16* Xb1  = (bf16*)p; p += (size_t)NN * DD * sizeof(bf16);
    bf16* Xb2  = (bf16*)p; p += (size_t)NN * DD * sizeof(bf16);
    bf16* hWb  = (bf16*)p; p += (size_t)NN * DD * sizeof(bf16);
    bf16* resb = (bf16*)p; p += (size_t)NN * DD * sizeof(bf16);
    bf16* Hb   = (bf16*)p; p += (size_t)NN * DD * sizeof(bf16);
    float* P   = (float*)p; p += (size_t)NN * GFEAT * sizeof(float);
    float* G1  = (float*)p; p += (size_t)NG * GFEAT * sizeof(float);
    float* G2  = (float*)p; p += (size_t)NG * GFEAT * sizeof(float);
    // 8 weight mats, 64K elems each; order: W1,Wr1,Ri1,Ro1,W2,Wr2,Ri2,Ro2
    bf16* Wbase = (bf16*)p; p += 8 * 65536 * sizeof(bf16);
    int* offs     = (int*)p; p += (NN + 1) * sizeof(int);
    int* partials = (int*)p; p += 64 * sizeof(int);
    int* cursor   = (int*)p; p += NN * sizeof(int);
    int* csr      = (int*)p;

    // weights -> bf16 transposed [n][k]; W1|Wr1 contiguous => fused Bt (512x256); same for W2|Wr2
    conv_w8_kernel<<<dim3(256, 8), 256, 0, stream>>>(W1, Wr1, Ri1, Ro1, W2, Wr2, Ri2, Ro2, Wbase);
    conv_x2_kernel<<<dim3((NN * DD / 4 + 255) / 256, 2), 256, 0, stream>>>(
        X1, X2, Xb1, Xb2, NN * DD / 4);

    run_branch(Xb1, src1, dst1, gid1, Wbase + 0 * 65536, b1, br1,
               Wbase + 2 * 65536, rbi1, Wbase + 3 * 65536, rbo1,
               G1, hWb, resb, Hb, P, offs, partials, cursor, csr, stream);
    run_branch(Xb2, src2, dst2, gid2, Wbase + 4 * 65536, b2, br2,
               Wbase + 6 * 65536, rbi2, Wbase + 7 * 65536, rbo2,
               G2, hWb, resb, Hb, P, offs, partials, cursor, csr, stream);

    predictor_kernel<<<(NG + 255) / 256, 256, 0, stream>>>(G1, G2, Wp, bp, (float*)d_out);
}

// Round 5
// 801.925 us; speedup vs baseline: 1.9944x; 1.1073x over previous
//
#include <hip/hip_runtime.h>

// Problem constants (fixed by reference)
#define NN 50000      // nodes
#define NE 800000     // edges
#define DD 256        // node feat dim
#define GFEAT 200     // graph feat dim
#define NG 512        // graphs

typedef __bf16 bf16;
typedef bf16 bf16x4 __attribute__((ext_vector_type(4)));
typedef bf16 bf16x8 __attribute__((ext_vector_type(8)));
typedef float f32x4 __attribute__((ext_vector_type(4)));

// async global->LDS, 16B per lane. HW dest = wave-uniform base + lane*16.
__device__ __forceinline__ void gl_lds16(const bf16* g, bf16* l) {
    __builtin_amdgcn_global_load_lds(
        (const __attribute__((address_space(1))) uint32_t*)(g),
        (__attribute__((address_space(3))) uint32_t*)(l), 16, 0, 0);
}

// swizzled fragment read: LDS [row][32k] where chunk c holds global chunk c^((row>>1)&3)
__device__ __forceinline__ bf16x8 frag_ld(const bf16* s, int R, int C) {
    return *(const bf16x8*)&s[R * 32 + ((C ^ ((R >> 1) & 3)) << 3)];
}

#define EPI_STRIDE 136   // bf16 elems; 272 B row stride (16B-aligned, bank-shift 4/row)

// ---------------------------------------------------------------------------
// conversions
// ---------------------------------------------------------------------------
__global__ __launch_bounds__(256) void conv_x2_kernel(const float* __restrict__ in0,
                                                      const float* __restrict__ in1,
                                                      bf16* __restrict__ out0,
                                                      bf16* __restrict__ out1, int n4) {
    const float* in = blockIdx.y ? in1 : in0;
    bf16* out = blockIdx.y ? out1 : out0;
    int i = blockIdx.x * 256 + threadIdx.x;
    if (i < n4) {
        float4 v = ((const float4*)in)[i];
        bf16x4 o;
        o[0] = (bf16)v.x; o[1] = (bf16)v.y; o[2] = (bf16)v.z; o[3] = (bf16)v.w;
        ((bf16x4*)out)[i] = o;
    }
}

// 8 weight matrices fp32 [K][N] -> bf16 [256][256] = [n][k] transposed, zero-padded.
__global__ __launch_bounds__(256) void conv_w8_kernel(
    const float* __restrict__ w0, const float* __restrict__ w1,
    const float* __restrict__ w2, const float* __restrict__ w3,
    const float* __restrict__ w4, const float* __restrict__ w5,
    const float* __restrict__ w6, const float* __restrict__ w7,
    bf16* __restrict__ out_base) {
    const float* ws[8] = {w0, w1, w2, w3, w4, w5, w6, w7};
    const int Ns[8] = {DD, DD, DD, GFEAT, DD, DD, DD, GFEAT};
    int m = blockIdx.y;
    const float* in = ws[m];
    int N = Ns[m];
    int idx = blockIdx.x * 256 + threadIdx.x;   // 0..65535 over [n][k]
    int n = idx >> 8, k = idx & 255;
    float v = (n < N) ? in[k * N + n] : 0.f;
    out_base[(size_t)m * 65536 + idx] = (bf16)v;
}

// ---------------------------------------------------------------------------
// CSR build (both branches batched via blockIdx.y)
// ---------------------------------------------------------------------------
__global__ __launch_bounds__(256) void zero2_kernel(int* __restrict__ p0,
                                                    int* __restrict__ p1, int n) {
    int* p = blockIdx.y ? p1 : p0;
    int i = blockIdx.x * 256 + threadIdx.x;
    if (i < n) p[i] = 0;
}

__global__ __launch_bounds__(256) void hist2_kernel(const int* __restrict__ d0,
                                                    const int* __restrict__ d1,
                                                    int* __restrict__ c0,
                                                    int* __restrict__ c1, int n) {
    const int* dst = blockIdx.y ? d1 : d0;
    int* counts = blockIdx.y ? c1 : c0;
    int e = blockIdx.x * 256 + threadIdx.x;
    if (e < n) atomicAdd(&counts[dst[e]], 1);
}

__global__ __launch_bounds__(256) void block_sum2_kernel(const int* __restrict__ c0,
                                                         const int* __restrict__ c1,
                                                         int* __restrict__ p0,
                                                         int* __restrict__ p1, int n) {
    const int* counts = blockIdx.y ? c1 : c0;
    int* partials = blockIdx.y ? p1 : p0;
    __shared__ int sred[4];
    int base = blockIdx.x * 1024;
    int t = threadIdx.x;
    int sum = 0;
#pragma unroll
    for (int r = 0; r < 4; r++) {
        int idx = base + r * 256 + t;
        if (idx < n) sum += counts[idx];
    }
    for (int off = 32; off > 0; off >>= 1) sum += __shfl_down(sum, off, 64);
    if ((t & 63) == 0) sred[t >> 6] = sum;
    __syncthreads();
    if (t == 0) partials[blockIdx.x] = sred[0] + sred[1] + sred[2] + sred[3];
}

__global__ __launch_bounds__(64) void scan_partials2_kernel(int* __restrict__ p0,
                                                            int* __restrict__ p1,
                                                            int* __restrict__ tot0,
                                                            int* __restrict__ tot1, int nb) {
    int* partials = blockIdx.y ? p1 : p0;
    int* total_out = blockIdx.y ? tot1 : tot0;
    int t = threadIdx.x;
    int orig = (t < nb) ? partials[t] : 0;
    int v = orig;
#pragma unroll
    for (int off = 1; off < 64; off <<= 1) {
        int u = __shfl_up(v, off, 64);
        if (t >= off) v += u;
    }
    if (t < nb) partials[t] = v - orig;
    if (t == 63) total_out[0] = v;
}

__global__ __launch_bounds__(256) void scan_apply2_kernel(int* __restrict__ o0,
                                                          int* __restrict__ o1,
                                                          const int* __restrict__ p0,
                                                          const int* __restrict__ p1,
                                                          int* __restrict__ cu0,
                                                          int* __restrict__ cu1, int n) {
    int* offs = blockIdx.y ? o1 : o0;
    const int* partials = blockIdx.y ? p1 : p0;
    int* cursor = blockIdx.y ? cu1 : cu0;
    __shared__ int ts[256];
    int base = blockIdx.x * 1024;
    int t = threadIdx.x;
    int c[4];
    int sum = 0;
#pragma unroll
    for (int r = 0; r < 4; r++) {
        int idx = base + t * 4 + r;
        c[r] = (idx < n) ? offs[idx] : 0;
        sum += c[r];
    }
    ts[t] = sum;
    __syncthreads();
    for (int off = 1; off < 256; off <<= 1) {
        int v = (t >= off) ? ts[t - off] : 0;
        __syncthreads();
        ts[t] += v;
        __syncthreads();
    }
    int run = partials[blockIdx.x] + ts[t] - sum;
#pragma unroll
    for (int r = 0; r < 4; r++) {
        int idx = base + t * 4 + r;
        if (idx < n) { offs[idx] = run; cursor[idx] = run; run += c[r]; }
    }
}

__global__ __launch_bounds__(256) void scatter2_kernel(const int* __restrict__ s0,
                                                       const int* __restrict__ s1,
                                                       const int* __restrict__ d0,
                                                       const int* __restrict__ d1,
                                                       int* __restrict__ cu0,
                                                       int* __restrict__ cu1,
                                                       int* __restrict__ csr0,
                                                       int* __restrict__ csr1, int n) {
    const int* src = blockIdx.y ? s1 : s0;
    const int* dst = blockIdx.y ? d1 : d0;
    int* cursor = blockIdx.y ? cu1 : cu0;
    int* csr = blockIdx.y ? csr1 : csr0;
    int e = blockIdx.x * 256 + threadIdx.x;
    if (e < n) {
        int pos = atomicAdd(&cursor[dst[e]], 1);
        csr[pos] = src[e];
    }
}

// ---------------------------------------------------------------------------
// bf16 MFMA GEMM (generic, bf16 out, storage width outW=256):
// C[M,0..N) = A[M,K] @ Bt[N,K]^T (+bias on cols<Nb) (+relu)
// 128x128 tile, BK=32, 256 threads (4 waves 2x2), swizzled LDS, LDS epilogue.
// ---------------------------------------------------------------------------
__global__ __launch_bounds__(256) void mfma_gemm_kernel(
    const bf16* __restrict__ A, const bf16* __restrict__ Bt,
    const float* __restrict__ bias, bf16* __restrict__ out,
    int M, int K, int Nb, int do_relu) {
    __shared__ bf16 smem[16384];     // As | Bs during K-loop; epilogue buffer after
    bf16* As = smem;
    bf16* Bs = smem + 8192;

    const int t    = threadIdx.x;
    const int lane = t & 63;
    const int w    = t >> 6;
    const int row0 = blockIdx.y * 128;
    const int col0 = blockIdx.x * 128;

    f32x4 acc[4][4] = {};
    const int wm = (w >> 1) * 64, wn = (w & 1) * 64;
    const int fm = lane & 15, fC = lane >> 4;

    for (int k0 = 0; k0 < K; k0 += 32) {
#pragma unroll
        for (int r = 0; r < 2; r++) {
            int flat = r * 256 + t;
            int fr = flat >> 2, fc = flat & 3;
            int fcg = fc ^ ((fr >> 1) & 3);          // swizzle
            int arow = row0 + fr;
            if (arow > M - 1) arow = M - 1;
            gl_lds16(&A[(size_t)arow * K + k0 + fcg * 8], &As[flat * 8]);
        }
#pragma unroll
        for (int r = 0; r < 2; r++) {
            int flat = r * 256 + t;
            int fr = flat >> 2, fc = flat & 3;
            int fcg = fc ^ ((fr >> 1) & 3);
            int brow = col0 + fr;                    // Bt padded
            gl_lds16(&Bt[(size_t)brow * K + k0 + fcg * 8], &Bs[flat * 8]);
        }
        __syncthreads();

        bf16x8 af[4], bfr[4];
#pragma unroll
        for (int i = 0; i < 4; i++) af[i] = frag_ld(As, wm + i * 16 + fm, fC);
#pragma unroll
        for (int i = 0; i < 4; i++) bfr[i] = frag_ld(Bs, wn + i * 16 + fm, fC);
#pragma unroll
        for (int i = 0; i < 4; i++)
#pragma unroll
            for (int j = 0; j < 4; j++)
                acc[i][j] = __builtin_amdgcn_mfma_f32_16x16x32_bf16(af[i], bfr[j], acc[i][j], 0, 0, 0);
        __syncthreads();
    }

    // bias per j (cols wn+fm+j*16)
    float bv[4];
#pragma unroll
    for (int j = 0; j < 4; j++) {
        int col = col0 + wn + fm + j * 16;
        bv[j] = (bias && col < Nb) ? bias[col] : 0.f;
    }

    // epilogue: 2 passes of 64 rows through LDS, then 16B coalesced stores
#pragma unroll
    for (int p = 0; p < 2; p++) {
        if ((w >> 1) == p) {
#pragma unroll
            for (int i = 0; i < 4; i++)
#pragma unroll
                for (int j = 0; j < 4; j++)
#pragma unroll
                    for (int r2 = 0; r2 < 4; r2++) {
                        int rl = i * 16 + (lane >> 4) * 4 + r2;   // 0..63
                        int cl = wn + fm + j * 16;                // 0..127
                        float v = acc[i][j][r2] + bv[j];
                        if (do_relu) v = fmaxf(v, 0.f);
                        smem[rl * EPI_STRIDE + cl] = (bf16)v;
                    }
        }
        __syncthreads();
#pragma unroll
        for (int q = 0; q < 4; q++) {
            int flat = q * 256 + t;
            int rl = flat >> 4, seg = flat & 15;
            int grow = row0 + p * 64 + rl;
            if (grow < M)
                *(bf16x8*)&out[(size_t)grow * 256 + col0 + seg * 8] =
                    *(const bf16x8*)&smem[rl * EPI_STRIDE + seg * 8];
        }
        __syncthreads();
    }
}

// Fused W+Wr GEMM: Bt2 is 512x256. cols 0-255 -> out_lo (no act), cols 256-511 ->
// out_hi = relu(.+bias_hi). grid (4, ceil(M/128)).
__global__ __launch_bounds__(256) void mfma_gemm_fused_kernel(
    const bf16* __restrict__ A, const bf16* __restrict__ Bt2,
    const float* __restrict__ bias_hi,
    bf16* __restrict__ out_lo, bf16* __restrict__ out_hi, int M) {
    __shared__ bf16 smem[16384];
    bf16* As = smem;
    bf16* Bs = smem + 8192;

    const int t    = threadIdx.x;
    const int lane = t & 63;
    const int w    = t >> 6;
    const int row0 = blockIdx.y * 128;
    const int col0 = blockIdx.x * 128;   // 0..384

    f32x4 acc[4][4] = {};
    const int wm = (w >> 1) * 64, wn = (w & 1) * 64;
    const int fm = lane & 15, fC = lane >> 4;

    for (int k0 = 0; k0 < 256; k0 += 32) {
#pragma unroll
        for (int r = 0; r < 2; r++) {
            int flat = r * 256 + t;
            int fr = flat >> 2, fc = flat & 3;
            int fcg = fc ^ ((fr >> 1) & 3);
            int arow = row0 + fr;
            if (arow > M - 1) arow = M - 1;
            gl_lds16(&A[(size_t)arow * 256 + k0 + fcg * 8], &As[flat * 8]);
        }
#pragma unroll
        for (int r = 0; r < 2; r++) {
            int flat = r * 256 + t;
            int fr = flat >> 2, fc = flat & 3;
            int fcg = fc ^ ((fr >> 1) & 3);
            int brow = col0 + fr;
            gl_lds16(&Bt2[(size_t)brow * 256 + k0 + fcg * 8], &Bs[flat * 8]);
        }
        __syncthreads();

        bf16x8 af[4], bfr[4];
#pragma unroll
        for (int i = 0; i < 4; i++) af[i] = frag_ld(As, wm + i * 16 + fm, fC);
#pragma unroll
        for (int i = 0; i < 4; i++) bfr[i] = frag_ld(Bs, wn + i * 16 + fm, fC);
#pragma unroll
        for (int i = 0; i < 4; i++)
#pragma unroll
            for (int j = 0; j < 4; j++)
                acc[i][j] = __builtin_amdgcn_mfma_f32_16x16x32_bf16(af[i], bfr[j], acc[i][j], 0, 0, 0);
        __syncthreads();
    }

    const bool hi = (col0 >= 256);          // block-uniform
    bf16* out = hi ? out_hi : out_lo;
    const int cb = hi ? col0 - 256 : col0;

    float bv[4];
#pragma unroll
    for (int j = 0; j < 4; j++) {
        int col = cb + wn + fm + j * 16;
        bv[j] = hi ? bias_hi[col] : 0.f;
    }

#pragma unroll
    for (int p = 0; p < 2; p++) {
        if ((w >> 1) == p) {
#pragma unroll
            for (int i = 0; i < 4; i++)
#pragma unroll
                for (int j = 0; j < 4; j++)
#pragma unroll
                    for (int r2 = 0; r2 < 4; r2++) {
                        int rl = i * 16 + (lane >> 4) * 4 + r2;
                        int cl = wn + fm + j * 16;
                        float v = acc[i][j][r2] + bv[j];
                        if (hi) v = fmaxf(v, 0.f);
                        smem[rl * EPI_STRIDE + cl] = (bf16)v;
                    }
        }
        __syncthreads();
#pragma unroll
        for (int q = 0; q < 4; q++) {
            int flat = q * 256 + t;
            int rl = flat >> 4, seg = flat & 15;
            int grow = row0 + p * 64 + rl;
            if (grow < M)
                *(bf16x8*)&out[(size_t)grow * 256 + cb + seg * 8] =
                    *(const bf16x8*)&smem[rl * EPI_STRIDE + seg * 8];
        }
        __syncthreads();
    }
}

// ---------------------------------------------------------------------------
// edge aggregation + combine (bf16 in/out, fp32 accumulate):
// H[v] = relu(sum_{e: dst=v} hW[src[e]] + b) + res[v]
// one wave per dst node; lane covers 8 feats (16B), half-waves cover 2 edges.
// ---------------------------------------------------------------------------
__global__ __launch_bounds__(256) void agg_combine_kernel(const bf16* __restrict__ hW,
                                                          const int* __restrict__ csr_src,
                                                          const int* __restrict__ offsets,
                                                          const float* __restrict__ bias,
                                                          const bf16* __restrict__ res,
                                                          bf16* __restrict__ H, int n_nodes) {
    int wave = threadIdx.x >> 6;
    int lane = threadIdx.x & 63;
    int node = blockIdx.x * 4 + wave;
    if (node >= n_nodes) return;
    int beg = offsets[node], end = offsets[node + 1];
    const int half = lane >> 5;
    const int fo   = (lane & 31) * 8;

    float acc[8] = {};
    int j = beg;
    for (; j + 2 + half < end; j += 4) {
        int s0 = csr_src[j + half];
        int s1 = csr_src[j + 2 + half];
        bf16x8 v0 = *(const bf16x8*)&hW[(size_t)s0 * DD + fo];
        bf16x8 v1 = *(const bf16x8*)&hW[(size_t)s1 * DD + fo];
#pragma unroll
        for (int q = 0; q < 8; q++) acc[q] += (float)v0[q];
#pragma unroll
        for (int q = 0; q < 8; q++) acc[q] += (float)v1[q];
    }
    for (; j + half < end; j += 2) {
        int s = csr_src[j + half];
        bf16x8 v = *(const bf16x8*)&hW[(size_t)s * DD + fo];
#pragma unroll
        for (int q = 0; q < 8; q++) acc[q] += (float)v[q];
    }
#pragma unroll
    for (int q = 0; q < 8; q++) acc[q] += __shfl_xor(acc[q], 32, 64);

    if (half == 0) {
        float4 b0 = *(const float4*)&bias[fo];
        float4 b1 = *(const float4*)&bias[fo + 4];
        bf16x8 rv = *(const bf16x8*)&res[(size_t)node * DD + fo];
        bf16x8 o;
        o[0] = (bf16)(fmaxf(acc[0] + b0.x, 0.f) + (float)rv[0]);
        o[1] = (bf16)(fmaxf(acc[1] + b0.y, 0.f) + (float)rv[1]);
        o[2] = (bf16)(fmaxf(acc[2] + b0.z, 0.f) + (float)rv[2]);
        o[3] = (bf16)(fmaxf(acc[3] + b0.w, 0.f) + (float)rv[3]);
        o[4] = (bf16)(fmaxf(acc[4] + b1.x, 0.f) + (float)rv[4]);
        o[5] = (bf16)(fmaxf(acc[5] + b1.y, 0.f) + (float)rv[5]);
        o[6] = (bf16)(fmaxf(acc[6] + b1.z, 0.f) + (float)rv[6]);
        o[7] = (bf16)(fmaxf(acc[7] + b1.w, 0.f) + (float)rv[7]);
        *(bf16x8*)&H[(size_t)node * DD + fo] = o;
    }
}

// ---------------------------------------------------------------------------
// per-graph segment sum of P[N_nodes, 256(stride)] bf16, cols<GFEAT; block per graph
// ---------------------------------------------------------------------------
__global__ __launch_bounds__(256) void graph_reduce_kernel(const bf16* __restrict__ P,
                                                           const int* __restrict__ gids,
                                                           float* __restrict__ G, int n_nodes) {
    int g = blockIdx.x;
    int lo = 0, hi = n_nodes;
    while (lo < hi) { int mid = (lo + hi) >> 1; if (gids[mid] < g) lo = mid + 1; else hi = mid; }
    int beg = lo;
    hi = n_nodes;
    while (lo < hi) { int mid = (lo + hi) >> 1; if (gids[mid] < g + 1) lo = mid + 1; else hi = mid; }
    int end = lo;

    int c = threadIdx.x;
    if (c < GFEAT) {
        float acc = 0.f;
        for (int r = beg; r < end; r++) acc += (float)P[(size_t)r * 256 + c];
        G[(size_t)g * GFEAT + c] = acc;
    }
}

__global__ __launch_bounds__(256) void predictor_kernel(const float* __restrict__ G1,
                                                        const float* __restrict__ G2,
                                                        const float* __restrict__ Wp,
                                                        const float* __restrict__ bp,
                                                        float* __restrict__ out) {
    int i = blockIdx.x * 256 + threadIdx.x;
    if (i >= NG) return;
    float acc = bp[0];
    for (int f = 0; f < GFEAT; f++)
        acc += (G1[i * GFEAT + f] + G2[i * GFEAT + f]) * Wp[f];
    out[i] = acc;
}

// ---------------------------------------------------------------------------
// host-side branch driver (CSR already built)
// ---------------------------------------------------------------------------
static void run_branch(const bf16* Xb, const int* gids,
                       const bf16* WWr, const float* b, const float* br,
                       const bf16* Rit, const float* rbi, const bf16* Rot, const float* rbo,
                       float* Gout, bf16* hWb, bf16* resb, bf16* Hb, bf16* P,
                       const int* offs, const int* csr, hipStream_t stream) {
    dim3 gf(4, (NN + 127) / 128);
    dim3 g2(2, (NN + 127) / 128);
    // hW = X @ W ; res = relu(X @ Wr + br)
    mfma_gemm_fused_kernel<<<gf, 256, 0, stream>>>(Xb, WWr, br, hWb, resb, NN);
    // H = relu(agg + b) + res
    agg_combine_kernel<<<(NN + 3) / 4, 256, 0, stream>>>(hWb, csr, offs, b, resb, Hb, NN);
    // R = relu(H @ Ri + rbi) -> reuse hWb
    mfma_gemm_kernel<<<g2, 256, 0, stream>>>(Hb, Rit, rbi, hWb, NN, DD, DD, 1);
    // P = R @ Ro + rbo (bf16, stride 256, cols<200 valid)
    mfma_gemm_kernel<<<g2, 256, 0, stream>>>(hWb, Rot, rbo, P, NN, DD, GFEAT, 0);
    // G = segment_sum(P, gids)
    graph_reduce_kernel<<<NG, 256, 0, stream>>>(P, gids, Gout, NN);
}

extern "C" void kernel_launch(void* const* d_in, const int* in_sizes, int n_in,
                              void* d_out, int out_size, void* d_ws, size_t ws_size,
                              hipStream_t stream) {
    const float* X1   = (const float*)d_in[0];
    const float* X2   = (const float*)d_in[2];
    const int*   src1 = (const int*)d_in[4];
    const int*   dst1 = (const int*)d_in[5];
    const int*   gid1 = (const int*)d_in[6];
    const int*   src2 = (const int*)d_in[7];
    const int*   dst2 = (const int*)d_in[8];
    const int*   gid2 = (const int*)d_in[9];
    const float* W1  = (const float*)d_in[10]; const float* b1  = (const float*)d_in[11];
    const float* Wr1 = (const float*)d_in[12]; const float* br1 = (const float*)d_in[13];
    const float* W2  = (const float*)d_in[14]; const float* b2  = (const float*)d_in[15];
    const float* Wr2 = (const float*)d_in[16]; const float* br2 = (const float*)d_in[17];
    const float* Ri1 = (const float*)d_in[18]; const float* rbi1 = (const float*)d_in[19];
    const float* Ro1 = (const float*)d_in[20]; const float* rbo1 = (const float*)d_in[21];
    const float* Ri2 = (const float*)d_in[22]; const float* rbi2 = (const float*)d_in[23];
    const float* Ro2 = (const float*)d_in[24]; const float* rbo2 = (const float*)d_in[25];
    const float* Wp  = (const float*)d_in[26]; const float* bp  = (const float*)d_in[27];

    // workspace layout
    char* p = (char*)d_ws;
    bf16* Xb1  = (bf16*)p; p += (size_t)NN * DD * sizeof(bf16);
    bf16* Xb2  = (bf16*)p; p += (size_t)NN * DD * sizeof(bf16);
    bf16* hWb  = (bf16*)p; p += (size_t)NN * DD * sizeof(bf16);
    bf16* resb = (bf16*)p; p += (size_t)NN * DD * sizeof(bf16);
    bf16* Hb   = (bf16*)p; p += (size_t)NN * DD * sizeof(bf16);
    bf16* P    = (bf16*)p; p += (size_t)NN * 256 * sizeof(bf16);
    float* G1  = (float*)p; p += (size_t)NG * GFEAT * sizeof(float);
    float* G2  = (float*)p; p += (size_t)NG * GFEAT * sizeof(float);
    // 8 weight mats; order: W1,Wr1,Ri1,Ro1,W2,Wr2,Ri2,Ro2 (W|Wr contiguous = fused Bt)
    bf16* Wbase = (bf16*)p; p += 8 * 65536 * sizeof(bf16);
    int* offs1     = (int*)p; p += (NN + 1) * sizeof(int);
    int* offs2     = (int*)p; p += (NN + 1) * sizeof(int);
    int* partials1 = (int*)p; p += 64 * sizeof(int);
    int* partials2 = (int*)p; p += 64 * sizeof(int);
    int* cursor1   = (int*)p; p += NN * sizeof(int);
    int* cursor2   = (int*)p; p += NN * sizeof(int);
    int* csr1      = (int*)p; p += NE * sizeof(int);
    int* csr2      = (int*)p;

    conv_w8_kernel<<<dim3(256, 8), 256, 0, stream>>>(W1, Wr1, Ri1, Ro1, W2, Wr2, Ri2, Ro2, Wbase);
    conv_x2_kernel<<<dim3((NN * DD / 4 + 255) / 256, 2), 256, 0, stream>>>(
        X1, X2, Xb1, Xb2, NN * DD / 4);

    // batched CSR build for both branches
    const int NB = (NN + 1023) / 1024;   // 49
    zero2_kernel<<<dim3((NN + 1 + 255) / 256, 2), 256, 0, stream>>>(offs1, offs2, NN + 1);
    hist2_kernel<<<dim3((NE + 255) / 256, 2), 256, 0, stream>>>(dst1, dst2, offs1, offs2, NE);
    block_sum2_kernel<<<dim3(NB, 2), 256, 0, stream>>>(offs1, offs2, partials1, partials2, NN);
    scan_partials2_kernel<<<dim3(1, 2), 64, 0, stream>>>(partials1, partials2,
                                                         &offs1[NN], &offs2[NN], NB);
    scan_apply2_kernel<<<dim3(NB, 2), 256, 0, stream>>>(offs1, offs2, partials1, partials2,
                                                        cursor1, cursor2, NN);
    scatter2_kernel<<<dim3((NE + 255) / 256, 2), 256, 0, stream>>>(
        src1, src2, dst1, dst2, cursor1, cursor2, csr1, csr2, NE);

    run_branch(Xb1, gid1, Wbase + 0 * 65536, b1, br1,
               Wbase + 2 * 65536, rbi1, Wbase + 3 * 65536, rbo1,
               G1, hWb, resb, Hb, P, offs1, csr1, stream);
    run_branch(Xb2, gid2, Wbase + 4 * 65536, b2, br2,
               Wbase + 6 * 65536, rbi2, Wbase + 7 * 65536, rbo2,
               G2, hWb, resb, Hb, P, offs2, csr2, stream);

    predictor_kernel<<<(NG + 255) / 256, 256, 0, stream>>>(G1, G2, Wp, bp, (float*)d_out);
}